// Round 10
// baseline (149.777 us; speedup 1.0000x reference)
//
#include <hip/hip_runtime.h>
#include <hip/hip_bf16.h>
#include <stdint.h>

typedef __hip_bfloat16 bf16;
typedef __attribute__((ext_vector_type(8))) short short8;
typedef __attribute__((ext_vector_type(4))) short bf16x4;
typedef __attribute__((ext_vector_type(4))) float f32x4;

#define EPS_ATTN 1e-6f
#define EPS_LN   1e-5f

__device__ __forceinline__ float b2f(short s) {
    return __builtin_bit_cast(float, (unsigned)((unsigned short)s) << 16);
}
__device__ __forceinline__ short f2b(float f) {
    return __builtin_bit_cast(short, __float2bfloat16(f));
}

// ---------------------------------------------------------------------------
// async global->LDS, 16B per lane. LDS dest = wave-uniform base + lane*16.
// ---------------------------------------------------------------------------
__device__ __forceinline__ void async16(const void* g, void* l) {
    __builtin_amdgcn_global_load_lds(
        (const __attribute__((address_space(1))) void*)g,
        (__attribute__((address_space(3))) void*)l,
        16, 0, 0);
}

// ---------------------------------------------------------------------------
// Prep: fp32->bf16 converts (x, source) + all 6 weight transposes, ONE launch.
// ---------------------------------------------------------------------------
__global__ __launch_bounds__(256)
void k_prep(const float* __restrict__ x, const float* __restrict__ src,
            bf16* __restrict__ x_bf, bf16* __restrict__ s_bf,
            const float* __restrict__ Wq, const float* __restrict__ Wk,
            const float* __restrict__ Wv, const float* __restrict__ Wm,
            const float* __restrict__ W1, const float* __restrict__ W2,
            bf16* __restrict__ WqT, bf16* __restrict__ WkT,
            bf16* __restrict__ WvT, bf16* __restrict__ WmT,
            bf16* __restrict__ W1T, bf16* __restrict__ W2T)
{
    __shared__ float tile[64][65];
    const int blk = blockIdx.x;
    if (blk < 8192) {
        const float* in = (blk < 4096) ? x : src;
        bf16* out       = (blk < 4096) ? x_bf : s_bf;
        const long id = (long)(blk & 4095) * 256 + threadIdx.x;
        const float4 a = ((const float4*)in)[id * 2];
        const float4 b = ((const float4*)in)[id * 2 + 1];
        short8 o;
        o[0] = f2b(a.x); o[1] = f2b(a.y); o[2] = f2b(a.z); o[3] = f2b(a.w);
        o[4] = f2b(b.x); o[5] = f2b(b.y); o[6] = f2b(b.z); o[7] = f2b(b.w);
        ((short8*)out)[id] = o;
        return;
    }
    const int b = blk - 8192;
    const float* W; bf16* WT; int K, N, local;
    if      (b < 16)  { W = Wq; WT = WqT; K = 256; N = 256; local = b; }
    else if (b < 32)  { W = Wk; WT = WkT; K = 256; N = 256; local = b - 16; }
    else if (b < 48)  { W = Wv; WT = WvT; K = 256; N = 256; local = b - 32; }
    else if (b < 64)  { W = Wm; WT = WmT; K = 256; N = 256; local = b - 48; }
    else if (b < 128) { W = W1; WT = W1T; K = 512; N = 512; local = b - 64; }
    else              { W = W2; WT = W2T; K = 512; N = 256; local = b - 128; }
    const int tk = K / 64;
    const int k0 = (local % tk) * 64, n0 = (local / tk) * 64;
    const int ty = threadIdx.x >> 4, tx = threadIdx.x & 15;
    #pragma unroll
    for (int i = 0; i < 4; ++i) {
        const int k = ty + i * 16;
        const float4 v = *(const float4*)&W[(long)(k0 + k) * N + n0 + tx * 4];
        tile[k][tx * 4 + 0] = v.x; tile[k][tx * 4 + 1] = v.y;
        tile[k][tx * 4 + 2] = v.z; tile[k][tx * 4 + 3] = v.w;
    }
    __syncthreads();
    #pragma unroll
    for (int i = 0; i < 4; ++i) {
        const int n = ty + i * 16;
        bf16x4 o;
        #pragma unroll
        for (int j = 0; j < 4; ++j) o[j] = f2b(tile[tx * 4 + j][n]);
        *(bf16x4*)&WT[(long)(n0 + n) * K + k0 + tx * 4] = o;
    }
}

// ---------------------------------------------------------------------------
// FUSED K/V projection + feature-map + partial-KV/Ksum (proven in R9).
// ---------------------------------------------------------------------------
__global__ __launch_bounds__(512)
void k_kvproj(const bf16* __restrict__ A, const bf16* __restrict__ BT,
              bf16* __restrict__ partKV, float* __restrict__ partKs,
              float escale)
{
    __shared__ __attribute__((aligned(16))) bf16 S[32768];   // 64 KB union
    bf16* Asm = S;
    bf16* Bsm = S + 8192;
    bf16* KT  = S;
    bf16* VT  = S + 16384;

    const int t = threadIdx.x, w = t >> 6, lane = t & 63;
    const int wm = w >> 2, wn = w & 3;
    const int flat = blockIdx.y * gridDim.x + blockIdx.x;   // 0..511
    const int swz  = (flat & 7) * 64 + (flat >> 3);         // bijective, XCD
    const int cid  = swz >> 1;
    const int hh   = swz & 1;
    const long row0 = (long)cid * 128;
    const int lr = lane >> 3, lc = (lane & 7) * 8;
    const int lg = lane >> 4, l15 = lane & 15;

    f32x4 acc[4][4] = {};

    for (int kt = 0; kt < 256; kt += 64) {
        #pragma unroll
        for (int i = 0; i < 2; ++i) {
            const int g = w * 2 + i;
            async16(A + (row0 + g * 8 + lr) * 256 + kt + lc, &Asm[g * 512]);
        }
        #pragma unroll
        for (int i = 0; i < 4; ++i) {
            const int g = w * 4 + i;
            const long brow = (g < 16)
                ? (long)(hh * 128 + g * 8 + lr)
                : (long)(256 + hh * 128 + (g - 16) * 8 + lr);
            async16(BT + brow * 256 + kt + lc, &Bsm[g * 512]);
        }
        __syncthreads();
        #pragma unroll
        for (int ks = 0; ks < 2; ++ks) {
            short8 a[4], b[4];
            #pragma unroll
            for (int m = 0; m < 4; ++m)
                a[m] = *(const short8*)&Asm[(wm*64 + m*16 + l15)*64 + ks*32 + lg*8];
            #pragma unroll
            for (int n = 0; n < 4; ++n)
                b[n] = *(const short8*)&Bsm[(wn*64 + n*16 + l15)*64 + ks*32 + lg*8];
            #pragma unroll
            for (int m = 0; m < 4; ++m)
                #pragma unroll
                for (int n = 0; n < 4; ++n)
                    acc[m][n] = __builtin_amdgcn_mfma_f32_16x16x32_bf16(a[m], b[n], acc[m][n], 0, 0, 0);
        }
        __syncthreads();
    }

    const bool isK = wn < 2;
    bf16* tile = isK ? KT : VT;
    #pragma unroll
    for (int m = 0; m < 4; ++m) {
        #pragma unroll
        for (int n = 0; n < 4; ++n) {
            #pragma unroll
            for (int r = 0; r < 4; ++r) {
                const int row = wm * 64 + m * 16 + lg * 4 + r;
                const int col = (wn & 1) * 64 + n * 16 + l15;
                float v = acc[m][n][r];
                if (isK) v = v > 0.f ? v + 1.f : __expf(v);
                else     v *= escale;
                tile[row * 128 + col] = __float2bfloat16(v);
            }
        }
    }
    __syncthreads();

    const int h_l = t >> 7;
    const int d   = (t & 127) >> 2;
    const int vg  = t & 3;
    float a2[8] = {};
    float ks = 0.f;
    #pragma unroll 4
    for (int row = 0; row < 128; ++row) {
        const float kd = __bfloat162float(KT[row * 128 + h_l * 32 + d]);
        ks += kd;
        const short8 vv = *(const short8*)&VT[row * 128 + h_l * 32 + vg * 8];
        #pragma unroll
        for (int u = 0; u < 8; ++u) a2[u] += kd * b2f(vv[u]);
    }
    short8 o;
    #pragma unroll
    for (int u = 0; u < 8; ++u) o[u] = f2b(a2[u]);
    *(short8*)&partKV[(long)cid * 8192 + (hh * 4 + h_l) * 1024 + d * 32 + vg * 8] = o;
    if (vg == 0) partKs[cid * 256 + (hh * 4 + h_l) * 32 + d] = ks;
}

// ---------------------------------------------------------------------------
// KV reduce stage 1: 64 chunks/batch -> 8 partials.
// ---------------------------------------------------------------------------
__global__ __launch_bounds__(256)
void k_kvred1(const bf16* __restrict__ partKV, const float* __restrict__ partKs,
              bf16* __restrict__ part2, float* __restrict__ part2Ks)
{
    const int bid = blockIdx.x;
    const int c8 = bid & 7, h = (bid >> 3) & 7, n = bid >> 6;
    const int t = threadIdx.x;
    const int d = t >> 3, vg = t & 7;
    float s[4] = {};
    #pragma unroll
    for (int j = 0; j < 8; ++j) {
        const int cid = n * 64 + c8 * 8 + j;
        const bf16x4 p = *(const bf16x4*)&partKV[(long)cid * 8192 + h * 1024 + d * 32 + vg * 4];
        #pragma unroll
        for (int jj = 0; jj < 4; ++jj) s[jj] += b2f(p[jj]);
    }
    bf16x4 o;
    #pragma unroll
    for (int jj = 0; jj < 4; ++jj) o[jj] = f2b(s[jj]);
    *(bf16x4*)&part2[(long)(c8 * 4 + n) * 8192 + h * 1024 + d * 32 + vg * 4] = o;
    if (vg == 0) {
        float ks = 0.f;
        #pragma unroll
        for (int j = 0; j < 8; ++j) {
            const int cid = n * 64 + c8 * 8 + j;
            ks += partKs[cid * 256 + h * 32 + d];
        }
        part2Ks[(c8 * 4 + n) * 256 + h * 32 + d] = ks;
    }
}

// ---------------------------------------------------------------------------
// KV reduce stage 2: 8 partials -> KVaug bf16 [n][h][32][48] (col 32 = Ksum)
// ---------------------------------------------------------------------------
__global__ __launch_bounds__(256)
void k_kvred2(const bf16* __restrict__ part2, const float* __restrict__ part2Ks,
              bf16* __restrict__ KVb)
{
    const int b = blockIdx.x;
    const int n = b >> 3, h = b & 7;
    const int t = threadIdx.x;
    const int d = t >> 3, vg = t & 7;
    float s[4] = {};
    #pragma unroll
    for (int c8 = 0; c8 < 8; ++c8) {
        const bf16x4 p = *(const bf16x4*)&part2[(long)(c8 * 4 + n) * 8192 + h * 1024 + d * 32 + vg * 4];
        #pragma unroll
        for (int j = 0; j < 4; ++j) s[j] += b2f(p[j]);
    }
    bf16* dst = KVb + ((long)n * 8 + h) * 1536 + d * 48;
    bf16x4 o;
    #pragma unroll
    for (int j = 0; j < 4; ++j) o[j] = f2b(s[j]);
    *(bf16x4*)&dst[vg * 4] = o;
    if (vg == 0) {
        float ks = 0.f;
        #pragma unroll
        for (int c8 = 0; c8 < 8; ++c8) ks += part2Ks[(c8 * 4 + n) * 256 + h * 32 + d];
        short8 z0 = {};
        z0[0] = f2b(ks);
        *(short8*)&dst[32] = z0;
        short8 zz = {};
        *(short8*)&dst[40] = zz;
    }
}

// ---------------------------------------------------------------------------
// MEGA: Q-proj + feature-map + attention + merge-GEMM + LN1 (proven in R8).
// ---------------------------------------------------------------------------
__global__ __launch_bounds__(512)
void k_qaml(const bf16* __restrict__ xb, const bf16* __restrict__ WqT,
            const bf16* __restrict__ WmT, const bf16* __restrict__ KVb,
            const float* __restrict__ g, const float* __restrict__ b,
            bf16* __restrict__ msgln)
{
    __shared__ __attribute__((aligned(16))) bf16 Asm[64 * 64];
    __shared__ __attribute__((aligned(16))) bf16 Bsm[256 * 64];
    __shared__ __attribute__((aligned(16))) bf16 QM[64 * 264];
    __shared__ float lnS[4][64];
    __shared__ float lnQ[4][64];
    const int t = threadIdx.x, w = t >> 6, lane = t & 63;
    const int wm = w >> 2, wn = w & 3;
    const long row0 = (long)blockIdx.x * 64;
    const int n_b = (int)(row0 >> 13);
    const int lr = lane >> 3, lc = (lane & 7) * 8;
    const int lg = lane >> 4, l15 = lane & 15;

    {
        f32x4 acc[2][4] = {};
        for (int kt = 0; kt < 256; kt += 64) {
            async16(xb + (row0 + w * 8 + lr) * 256 + kt + lc, &Asm[w * 512]);
            #pragma unroll
            for (int i = 0; i < 4; ++i) {
                const int ch = i * 8 + w;
                async16(WqT + (long)(ch * 8 + lr) * 256 + kt + lc, &Bsm[ch * 512]);
            }
            __syncthreads();
            #pragma unroll
            for (int ks = 0; ks < 2; ++ks) {
                short8 a[2], bb[4];
                #pragma unroll
                for (int m = 0; m < 2; ++m)
                    a[m] = *(const short8*)&Asm[(wm*32 + m*16 + l15)*64 + ks*32 + lg*8];
                #pragma unroll
                for (int n = 0; n < 4; ++n)
                    bb[n] = *(const short8*)&Bsm[(wn*64 + n*16 + l15)*64 + ks*32 + lg*8];
                #pragma unroll
                for (int m = 0; m < 2; ++m)
                    #pragma unroll
                    for (int n = 0; n < 4; ++n)
                        acc[m][n] = __builtin_amdgcn_mfma_f32_16x16x32_bf16(a[m], bb[n], acc[m][n], 0, 0, 0);
            }
            __syncthreads();
        }
        #pragma unroll
        for (int m = 0; m < 2; ++m) {
            #pragma unroll
            for (int n = 0; n < 4; ++n) {
                #pragma unroll
                for (int r = 0; r < 4; ++r) {
                    const int row = wm * 32 + m * 16 + lg * 4 + r;
                    const int col = wn * 64 + n * 16 + l15;
                    float v = acc[m][n][r];
                    v = v > 0.f ? v + 1.f : __expf(v);
                    QM[row * 264 + col] = __float2bfloat16(v);
                }
            }
        }
    }
    __syncthreads();

    {
        const bf16* kvh = KVb + (long)n_b * 12288 + w * 1536;
        short8 b0, b1, bz;
        #pragma unroll
        for (int j = 0; j < 8; ++j) {
            const int drow = (lg * 8 + j) * 48;
            b0[j] = __builtin_bit_cast(short, kvh[drow + l15]);
            b1[j] = __builtin_bit_cast(short, kvh[drow + 16 + l15]);
            bz[j] = __builtin_bit_cast(short, kvh[drow + 32 + l15]);
        }
        f32x4 ra0[4], ra1[4];
        #pragma unroll
        for (int m2 = 0; m2 < 4; ++m2) {
            const short8 a = *(const short8*)&QM[(m2 * 16 + l15) * 264 + w * 32 + lg * 8];
            f32x4 a0 = {}, a1 = {}, az = {};
            a0 = __builtin_amdgcn_mfma_f32_16x16x32_bf16(a, b0, a0, 0, 0, 0);
            a1 = __builtin_amdgcn_mfma_f32_16x16x32_bf16(a, b1, a1, 0, 0, 0);
            az = __builtin_amdgcn_mfma_f32_16x16x32_bf16(a, bz, az, 0, 0, 0);
            #pragma unroll
            for (int r = 0; r < 4; ++r) {
                const float z   = __shfl(az[r], lane & 48);
                const float inv = 8192.f / (z + EPS_ATTN);
                ra0[m2][r] = a0[r] * inv;
                ra1[m2][r] = a1[r] * inv;
            }
        }
        __syncthreads();
        #pragma unroll
        for (int m2 = 0; m2 < 4; ++m2) {
            #pragma unroll
            for (int r = 0; r < 4; ++r) {
                const int row = m2 * 16 + lg * 4 + r;
                QM[row * 264 + w * 32 + l15]      = __float2bfloat16(ra0[m2][r]);
                QM[row * 264 + w * 32 + 16 + l15] = __float2bfloat16(ra1[m2][r]);
            }
        }
    }
    __syncthreads();

    f32x4 acc[2][4] = {};
    for (int kt = 0; kt < 256; kt += 64) {
        #pragma unroll
        for (int i = 0; i < 4; ++i) {
            const int ch = i * 8 + w;
            async16(WmT + (long)(ch * 8 + lr) * 256 + kt + lc, &Bsm[ch * 512]);
        }
        __syncthreads();
        #pragma unroll
        for (int ks = 0; ks < 2; ++ks) {
            short8 a[2], bb[4];
            #pragma unroll
            for (int m = 0; m < 2; ++m)
                a[m] = *(const short8*)&QM[(wm*32 + m*16 + l15) * 264 + kt + ks*32 + lg*8];
            #pragma unroll
            for (int n = 0; n < 4; ++n)
                bb[n] = *(const short8*)&Bsm[(wn*64 + n*16 + l15)*64 + ks*32 + lg*8];
            #pragma unroll
            for (int m = 0; m < 2; ++m)
                #pragma unroll
                for (int n = 0; n < 4; ++n)
                    acc[m][n] = __builtin_amdgcn_mfma_f32_16x16x32_bf16(a[m], bb[n], acc[m][n], 0, 0, 0);
        }
        __syncthreads();
    }

    #pragma unroll
    for (int m = 0; m < 2; ++m) {
        #pragma unroll
        for (int r = 0; r < 4; ++r) {
            float ls = 0.f, lq = 0.f;
            #pragma unroll
            for (int n = 0; n < 4; ++n) {
                const float v = acc[m][n][r];
                ls += v; lq += v * v;
            }
            #pragma unroll
            for (int o = 1; o < 16; o <<= 1) {
                ls += __shfl_xor(ls, o);
                lq += __shfl_xor(lq, o);
            }
            if (l15 == 0) {
                const int row = wm * 32 + m * 16 + lg * 4 + r;
                lnS[wn][row] = ls;
                lnQ[wn][row] = lq;
            }
        }
    }
    __syncthreads();

    float gv[4], bv[4];
    #pragma unroll
    for (int n = 0; n < 4; ++n) {
        const int col = wn * 64 + n * 16 + l15;
        gv[n] = g[col]; bv[n] = b[col];
    }
    #pragma unroll
    for (int m = 0; m < 2; ++m) {
        #pragma unroll
        for (int r = 0; r < 4; ++r) {
            const int row = wm * 32 + m * 16 + lg * 4 + r;
            const float S  = lnS[0][row] + lnS[1][row] + lnS[2][row] + lnS[3][row];
            const float Qq = lnQ[0][row] + lnQ[1][row] + lnQ[2][row] + lnQ[3][row];
            const float mean = S * (1.f / 256.f);
            const float var  = Qq * (1.f / 256.f) - mean * mean;
            const float rstd = rsqrtf(var + EPS_LN);
            const long grow = row0 + row;
            #pragma unroll
            for (int n = 0; n < 4; ++n) {
                const int col = wn * 64 + n * 16 + l15;
                const float y = (acc[m][n][r] - mean) * rstd * gv[n] + bv[n];
                msgln[grow * 256 + col] = __float2bfloat16(y);
            }
        }
    }
}

// ---------------------------------------------------------------------------
// FUSED MLP v2: out = x + LN2( relu([x_bf|msgln] @ W1) @ W2 ).
// 64-row blocks, 512 thr, 8 waves. Fixes R5's k_mlp failures:
//  - B operands LDS-staged via global_load_lds (not register-direct global)
//  - t kept in LDS with unit-granular XOR swizzle: elem addr =
//    row*512 + ((col>>3 ^ (row&7))<<3) + (col&7)  -> b128 reads 2-way max
//  - double-buffered staging (issue next step BEFORE compute; __syncthreads
//    drains) since 146KB LDS -> 1 block/CU (no cross-block overlap).
// Phase A: 2 col-passes of 256 (W1T 32KB/K-step); Phase B: W2 (32KB/K-step).
// ---------------------------------------------------------------------------
__global__ __launch_bounds__(512)
void k_mlp2(const bf16* __restrict__ A0, const bf16* __restrict__ A1,
            const bf16* __restrict__ W1T, const bf16* __restrict__ W2T,
            const float* __restrict__ g, const float* __restrict__ b,
            const float* __restrict__ xres, float* __restrict__ out)
{
    __shared__ __attribute__((aligned(16))) bf16 SA[2][4096];    // 2 x 8 KB
    __shared__ __attribute__((aligned(16))) bf16 SB[2][16384];   // 2 x 32 KB
    __shared__ __attribute__((aligned(16))) bf16 T[32768];       // 64 KB
    __shared__ float lnS[4][64];
    __shared__ float lnQ[4][64];

    const int t = threadIdx.x, w = t >> 6, lane = t & 63;
    const long row0 = (long)blockIdx.x * 64;
    const int lg = lane >> 4, l15 = lane & 15;
    const int srow = lane >> 3, skoff = (lane & 7) * 8;

    int buf = 0;

    // ---- staging helpers (macros to keep wave-uniform LDS dest) ----
    #define STAGE_A(B_, KT_) {                                                 \
        const bf16* Asrc_ = ((KT_) < 256) ? A0 : A1;                           \
        const int kk_ = (KT_) & 255;                                           \
        async16(Asrc_ + (row0 + w * 8 + srow) * 256 + kk_ + skoff,             \
                &SA[B_][w * 512]); }
    #define STAGE_B1(B_, P_, KT_) {                                            \
        _Pragma("unroll")                                                      \
        for (int i_ = 0; i_ < 4; ++i_) {                                       \
            const int g_ = w * 4 + i_;                                         \
            async16(W1T + (long)((P_) * 256 + g_ * 8 + srow) * 512 + (KT_) + skoff, \
                    &SB[B_][g_ * 512]); } }
    #define STAGE_B2(B_, KT_) {                                                \
        _Pragma("unroll")                                                      \
        for (int i_ = 0; i_ < 4; ++i_) {                                       \
            const int g_ = w * 4 + i_;                                         \
            async16(W2T + (long)(g_ * 8 + srow) * 512 + (KT_) + skoff,         \
                    &SB[B_][g_ * 512]); } }

    // ================= phase A: t = relu([x|msgln] @ W1) =================
    STAGE_A(0, 0);
    STAGE_B1(0, 0, 0);
    __syncthreads();

    for (int p = 0; p < 2; ++p) {
        f32x4 acc[4][2] = {};
        for (int k8 = 0; k8 < 8; ++k8) {
            const int s = p * 8 + k8;
            if (s < 15) {
                const int ns = s + 1;
                STAGE_A(buf ^ 1, (ns & 7) * 64);
                STAGE_B1(buf ^ 1, ns >> 3, (ns & 7) * 64);
            }
            #pragma unroll
            for (int ks = 0; ks < 2; ++ks) {
                short8 a[4], bb[2];
                #pragma unroll
                for (int m = 0; m < 4; ++m)
                    a[m] = *(const short8*)&SA[buf][(m*16 + l15)*64 + ks*32 + lg*8];
                #pragma unroll
                for (int n = 0; n < 2; ++n)
                    bb[n] = *(const short8*)&SB[buf][(w*32 + n*16 + l15)*64 + ks*32 + lg*8];
                #pragma unroll
                for (int m = 0; m < 4; ++m)
                    #pragma unroll
                    for (int n = 0; n < 2; ++n)
                        acc[m][n] = __builtin_amdgcn_mfma_f32_16x16x32_bf16(a[m], bb[n], acc[m][n], 0, 0, 0);
            }
            __syncthreads();
            buf ^= 1;
        }
        // relu + write t (swizzled). Safe: T untouched by staging; barriers
        // downstream order these LDS writes before phase-B reads.
        #pragma unroll
        for (int m = 0; m < 4; ++m) {
            #pragma unroll
            for (int n = 0; n < 2; ++n) {
                #pragma unroll
                for (int r = 0; r < 4; ++r) {
                    const int row = m * 16 + lg * 4 + r;
                    const int col = p * 256 + w * 32 + n * 16 + l15;
                    float v = acc[m][n][r];
                    v = v > 0.f ? v : 0.f;
                    T[row * 512 + (((col >> 3) ^ (row & 7)) << 3) + (col & 7)] =
                        __float2bfloat16(v);
                }
            }
        }
    }

    // ================= phase B: msg2 = t @ W2, + LN2 + residual ==========
    const int wm = w >> 2, wn = w & 3;
    STAGE_B2(buf, 0);
    __syncthreads();

    f32x4 acc2[2][4] = {};
    for (int k8 = 0; k8 < 8; ++k8) {
        if (k8 < 7) STAGE_B2(buf ^ 1, (k8 + 1) * 64);
        #pragma unroll
        for (int ks = 0; ks < 2; ++ks) {
            short8 a[2], bb[4];
            #pragma unroll
            for (int m = 0; m < 2; ++m) {
                const int row = wm * 32 + m * 16 + l15;
                const int c0  = k8 * 64 + ks * 32 + lg * 8;
                a[m] = *(const short8*)&T[row * 512 + (((c0 >> 3) ^ (row & 7)) << 3)];
            }
            #pragma unroll
            for (int n = 0; n < 4; ++n)
                bb[n] = *(const short8*)&SB[buf][(wn*64 + n*16 + l15)*64 + ks*32 + lg*8];
            #pragma unroll
            for (int m = 0; m < 2; ++m)
                #pragma unroll
                for (int n = 0; n < 4; ++n)
                    acc2[m][n] = __builtin_amdgcn_mfma_f32_16x16x32_bf16(a[m], bb[n], acc2[m][n], 0, 0, 0);
        }
        __syncthreads();
        buf ^= 1;
    }

    #pragma unroll
    for (int m = 0; m < 2; ++m) {
        #pragma unroll
        for (int r = 0; r < 4; ++r) {
            float ls = 0.f, lq = 0.f;
            #pragma unroll
            for (int n = 0; n < 4; ++n) {
                const float v = acc2[m][n][r];
                ls += v; lq += v * v;
            }
            #pragma unroll
            for (int o = 1; o < 16; o <<= 1) {
                ls += __shfl_xor(ls, o);
                lq += __shfl_xor(lq, o);
            }
            if (l15 == 0) {
                const int row = wm * 32 + m * 16 + lg * 4 + r;
                lnS[wn][row] = ls;
                lnQ[wn][row] = lq;
            }
        }
    }
    __syncthreads();

    float gv[4], bv[4];
    #pragma unroll
    for (int n = 0; n < 4; ++n) {
        const int col = wn * 64 + n * 16 + l15;
        gv[n] = g[col]; bv[n] = b[col];
    }
    #pragma unroll
    for (int m = 0; m < 2; ++m) {
        #pragma unroll
        for (int r = 0; r < 4; ++r) {
            const int row = wm * 32 + m * 16 + lg * 4 + r;
            const float S  = lnS[0][row] + lnS[1][row] + lnS[2][row] + lnS[3][row];
            const float Qq = lnQ[0][row] + lnQ[1][row] + lnQ[2][row] + lnQ[3][row];
            const float mean = S * (1.f / 256.f);
            const float var  = Qq * (1.f / 256.f) - mean * mean;
            const float rstd = rsqrtf(var + EPS_LN);
            const long grow = row0 + row;
            #pragma unroll
            for (int n = 0; n < 4; ++n) {
                const int col = wn * 64 + n * 16 + l15;
                const float y = (acc2[m][n][r] - mean) * rstd * gv[n] + bv[n];
                out[grow * 256 + col] = xres[grow * 256 + col] + y;
            }
        }
    }
    #undef STAGE_A
    #undef STAGE_B1
    #undef STAGE_B2
}

// ---------------------------------------------------------------------------
extern "C" void kernel_launch(void* const* d_in, const int* in_sizes, int n_in,
                              void* d_out, int out_size, void* d_ws, size_t ws_size,
                              hipStream_t stream)
{
    const float* x      = (const float*)d_in[0];
    const float* source = (const float*)d_in[1];
    const float* Wq     = (const float*)d_in[2];
    const float* Wk     = (const float*)d_in[3];
    const float* Wv     = (const float*)d_in[4];
    const float* Wm     = (const float*)d_in[5];
    const float* W1     = (const float*)d_in[6];
    const float* W2     = (const float*)d_in[7];
    const float* g1     = (const float*)d_in[8];
    const float* b1     = (const float*)d_in[9];
    const float* g2     = (const float*)d_in[10];
    const float* b2     = (const float*)d_in[11];
    float* out = (float*)d_out;

    const size_t U = 32768ull * 256ull;
    char* w = (char*)d_ws;

    // slots (16 MB each); lifetimes:
    bf16* x_bf  = (bf16*)(w + 0 * U * 2);   // alive through k_mlp2
    bf16* s_bf  = (bf16*)(w + 1 * U * 2);   // dead after k_kvproj
    bf16* msgln = (bf16*)(w + 2 * U * 2);   // qaml out, alive through k_mlp2

    char* wx = w + 7 * U * 2;
    bf16* WqT = (bf16*)wx; wx += 65536 * 2;
    bf16* WkT = (bf16*)wx; wx += 65536 * 2;   // contiguous with WvT -> [512][256]
    bf16* WvT = (bf16*)wx; wx += 65536 * 2;
    bf16* WmT = (bf16*)wx; wx += 65536 * 2;
    bf16* W1T = (bf16*)wx; wx += 262144 * 2;
    bf16* W2T = (bf16*)wx; wx += 131072 * 2;
    bf16* partKV = (bf16*)wx; wx += 2097152 * 2;   // 256 cid x 8192
    float* partKs = (float*)wx; wx += 65536 * 4;   // 256 cid x 256
    bf16* part2  = (bf16*)wx; wx += 262144 * 2;    // 8 x 4 x 8192
    float* part2Ks = (float*)wx; wx += 8192 * 4;   // 8 x 4 x 256
    bf16* KVb    = (bf16*)wx; wx += 49152 * 2;     // [n][h][32][48]

    const dim3 blk(256);

    // 1) prep: converts + all weight transposes (one launch)
    k_prep<<<8352, blk, 0, stream>>>(x, source, x_bf, s_bf,
                                     Wq, Wk, Wv, Wm, W1, W2,
                                     WqT, WkT, WvT, WmT, W1T, W2T);

    // 2) FUSED K/V projection + partial KV/Ksum
    k_kvproj<<<dim3(256, 2), dim3(512), 0, stream>>>(s_bf, WkT, partKV, partKs,
                                                     1.f / 8192.f);

    // 3) reduce partials -> KVaug
    k_kvred1<<<256, blk, 0, stream>>>(partKV, partKs, part2, part2Ks);
    k_kvred2<<<32, blk, 0, stream>>>(part2, part2Ks, KVb);

    // 4) MEGA: Q-proj + attn + merge + LN1 -> msgln
    k_qaml<<<512, dim3(512), 0, stream>>>(x_bf, WqT, WmT, KVb, g1, b1, msgln);

    // 5) FUSED MLP v2: out = x + LN2(relu([x_bf|msgln]@W1)@W2), no t_bf
    k_mlp2<<<512, dim3(512), 0, stream>>>(x_bf, msgln, W1T, W2T, g2, b2, x, out);
}

// Round 11
// 131.408 us; speedup vs baseline: 1.1398x; 1.1398x over previous
//
#include <hip/hip_runtime.h>
#include <hip/hip_bf16.h>
#include <stdint.h>

typedef __hip_bfloat16 bf16;
typedef __attribute__((ext_vector_type(8))) short short8;
typedef __attribute__((ext_vector_type(4))) short bf16x4;
typedef __attribute__((ext_vector_type(4))) float f32x4;

#define EPS_ATTN 1e-6f
#define EPS_LN   1e-5f

__device__ __forceinline__ float b2f(short s) {
    return __builtin_bit_cast(float, (unsigned)((unsigned short)s) << 16);
}
__device__ __forceinline__ short f2b(float f) {
    return __builtin_bit_cast(short, __float2bfloat16(f));
}

// ---------------------------------------------------------------------------
// async global->LDS, 16B per lane. LDS dest = wave-uniform base + lane*16.
// ---------------------------------------------------------------------------
__device__ __forceinline__ void async16(const void* g, void* l) {
    __builtin_amdgcn_global_load_lds(
        (const __attribute__((address_space(1))) void*)g,
        (__attribute__((address_space(3))) void*)l,
        16, 0, 0);
}

// ---------------------------------------------------------------------------
// Prep: fp32->bf16 converts (x, source) + all 6 weight transposes, ONE launch.
// ---------------------------------------------------------------------------
__global__ __launch_bounds__(256)
void k_prep(const float* __restrict__ x, const float* __restrict__ src,
            bf16* __restrict__ x_bf, bf16* __restrict__ s_bf,
            const float* __restrict__ Wq, const float* __restrict__ Wk,
            const float* __restrict__ Wv, const float* __restrict__ Wm,
            const float* __restrict__ W1, const float* __restrict__ W2,
            bf16* __restrict__ WqT, bf16* __restrict__ WkT,
            bf16* __restrict__ WvT, bf16* __restrict__ WmT,
            bf16* __restrict__ W1T, bf16* __restrict__ W2T)
{
    __shared__ float tile[64][65];
    const int blk = blockIdx.x;
    if (blk < 8192) {
        const float* in = (blk < 4096) ? x : src;
        bf16* out       = (blk < 4096) ? x_bf : s_bf;
        const long id = (long)(blk & 4095) * 256 + threadIdx.x;
        const float4 a = ((const float4*)in)[id * 2];
        const float4 b = ((const float4*)in)[id * 2 + 1];
        short8 o;
        o[0] = f2b(a.x); o[1] = f2b(a.y); o[2] = f2b(a.z); o[3] = f2b(a.w);
        o[4] = f2b(b.x); o[5] = f2b(b.y); o[6] = f2b(b.z); o[7] = f2b(b.w);
        ((short8*)out)[id] = o;
        return;
    }
    const int b = blk - 8192;
    const float* W; bf16* WT; int K, N, local;
    if      (b < 16)  { W = Wq; WT = WqT; K = 256; N = 256; local = b; }
    else if (b < 32)  { W = Wk; WT = WkT; K = 256; N = 256; local = b - 16; }
    else if (b < 48)  { W = Wv; WT = WvT; K = 256; N = 256; local = b - 32; }
    else if (b < 64)  { W = Wm; WT = WmT; K = 256; N = 256; local = b - 48; }
    else if (b < 128) { W = W1; WT = W1T; K = 512; N = 512; local = b - 64; }
    else              { W = W2; WT = W2T; K = 512; N = 256; local = b - 128; }
    const int tk = K / 64;
    const int k0 = (local % tk) * 64, n0 = (local / tk) * 64;
    const int ty = threadIdx.x >> 4, tx = threadIdx.x & 15;
    #pragma unroll
    for (int i = 0; i < 4; ++i) {
        const int k = ty + i * 16;
        const float4 v = *(const float4*)&W[(long)(k0 + k) * N + n0 + tx * 4];
        tile[k][tx * 4 + 0] = v.x; tile[k][tx * 4 + 1] = v.y;
        tile[k][tx * 4 + 2] = v.z; tile[k][tx * 4 + 3] = v.w;
    }
    __syncthreads();
    #pragma unroll
    for (int i = 0; i < 4; ++i) {
        const int n = ty + i * 16;
        bf16x4 o;
        #pragma unroll
        for (int j = 0; j < 4; ++j) o[j] = f2b(tile[tx * 4 + j][n]);
        *(bf16x4*)&WT[(long)(n0 + n) * K + k0 + tx * 4] = o;
    }
}

// ---------------------------------------------------------------------------
// FUSED K/V projection + feature-map + partial-KV/Ksum (proven in R9).
// ---------------------------------------------------------------------------
__global__ __launch_bounds__(512)
void k_kvproj(const bf16* __restrict__ A, const bf16* __restrict__ BT,
              bf16* __restrict__ partKV, float* __restrict__ partKs,
              float escale)
{
    __shared__ __attribute__((aligned(16))) bf16 S[32768];   // 64 KB union
    bf16* Asm = S;
    bf16* Bsm = S + 8192;
    bf16* KT  = S;
    bf16* VT  = S + 16384;

    const int t = threadIdx.x, w = t >> 6, lane = t & 63;
    const int wm = w >> 2, wn = w & 3;
    const int flat = blockIdx.y * gridDim.x + blockIdx.x;   // 0..511
    const int swz  = (flat & 7) * 64 + (flat >> 3);         // bijective, XCD
    const int cid  = swz >> 1;
    const int hh   = swz & 1;
    const long row0 = (long)cid * 128;
    const int lr = lane >> 3, lc = (lane & 7) * 8;
    const int lg = lane >> 4, l15 = lane & 15;

    f32x4 acc[4][4] = {};

    for (int kt = 0; kt < 256; kt += 64) {
        #pragma unroll
        for (int i = 0; i < 2; ++i) {
            const int g = w * 2 + i;
            async16(A + (row0 + g * 8 + lr) * 256 + kt + lc, &Asm[g * 512]);
        }
        #pragma unroll
        for (int i = 0; i < 4; ++i) {
            const int g = w * 4 + i;
            const long brow = (g < 16)
                ? (long)(hh * 128 + g * 8 + lr)
                : (long)(256 + hh * 128 + (g - 16) * 8 + lr);
            async16(BT + brow * 256 + kt + lc, &Bsm[g * 512]);
        }
        __syncthreads();
        #pragma unroll
        for (int ks = 0; ks < 2; ++ks) {
            short8 a[4], b[4];
            #pragma unroll
            for (int m = 0; m < 4; ++m)
                a[m] = *(const short8*)&Asm[(wm*64 + m*16 + l15)*64 + ks*32 + lg*8];
            #pragma unroll
            for (int n = 0; n < 4; ++n)
                b[n] = *(const short8*)&Bsm[(wn*64 + n*16 + l15)*64 + ks*32 + lg*8];
            #pragma unroll
            for (int m = 0; m < 4; ++m)
                #pragma unroll
                for (int n = 0; n < 4; ++n)
                    acc[m][n] = __builtin_amdgcn_mfma_f32_16x16x32_bf16(a[m], b[n], acc[m][n], 0, 0, 0);
        }
        __syncthreads();
    }

    const bool isK = wn < 2;
    bf16* tile = isK ? KT : VT;
    #pragma unroll
    for (int m = 0; m < 4; ++m) {
        #pragma unroll
        for (int n = 0; n < 4; ++n) {
            #pragma unroll
            for (int r = 0; r < 4; ++r) {
                const int row = wm * 64 + m * 16 + lg * 4 + r;
                const int col = (wn & 1) * 64 + n * 16 + l15;
                float v = acc[m][n][r];
                if (isK) v = v > 0.f ? v + 1.f : __expf(v);
                else     v *= escale;
                tile[row * 128 + col] = __float2bfloat16(v);
            }
        }
    }
    __syncthreads();

    const int h_l = t >> 7;
    const int d   = (t & 127) >> 2;
    const int vg  = t & 3;
    float a2[8] = {};
    float ks = 0.f;
    #pragma unroll 4
    for (int row = 0; row < 128; ++row) {
        const float kd = __bfloat162float(KT[row * 128 + h_l * 32 + d]);
        ks += kd;
        const short8 vv = *(const short8*)&VT[row * 128 + h_l * 32 + vg * 8];
        #pragma unroll
        for (int u = 0; u < 8; ++u) a2[u] += kd * b2f(vv[u]);
    }
    short8 o;
    #pragma unroll
    for (int u = 0; u < 8; ++u) o[u] = f2b(a2[u]);
    *(short8*)&partKV[(long)cid * 8192 + (hh * 4 + h_l) * 1024 + d * 32 + vg * 8] = o;
    if (vg == 0) partKs[cid * 256 + (hh * 4 + h_l) * 32 + d] = ks;
}

// ---------------------------------------------------------------------------
// KV reduce stage 1: 64 chunks/batch -> 8 partials.
// ---------------------------------------------------------------------------
__global__ __launch_bounds__(256)
void k_kvred1(const bf16* __restrict__ partKV, const float* __restrict__ partKs,
              bf16* __restrict__ part2, float* __restrict__ part2Ks)
{
    const int bid = blockIdx.x;
    const int c8 = bid & 7, h = (bid >> 3) & 7, n = bid >> 6;
    const int t = threadIdx.x;
    const int d = t >> 3, vg = t & 7;
    float s[4] = {};
    #pragma unroll
    for (int j = 0; j < 8; ++j) {
        const int cid = n * 64 + c8 * 8 + j;
        const bf16x4 p = *(const bf16x4*)&partKV[(long)cid * 8192 + h * 1024 + d * 32 + vg * 4];
        #pragma unroll
        for (int jj = 0; jj < 4; ++jj) s[jj] += b2f(p[jj]);
    }
    bf16x4 o;
    #pragma unroll
    for (int jj = 0; jj < 4; ++jj) o[jj] = f2b(s[jj]);
    *(bf16x4*)&part2[(long)(c8 * 4 + n) * 8192 + h * 1024 + d * 32 + vg * 4] = o;
    if (vg == 0) {
        float ks = 0.f;
        #pragma unroll
        for (int j = 0; j < 8; ++j) {
            const int cid = n * 64 + c8 * 8 + j;
            ks += partKs[cid * 256 + h * 32 + d];
        }
        part2Ks[(c8 * 4 + n) * 256 + h * 32 + d] = ks;
    }
}

// ---------------------------------------------------------------------------
// KV reduce stage 2: 8 partials -> KVaug bf16 [n][h][32][48] (col 32 = Ksum)
// ---------------------------------------------------------------------------
__global__ __launch_bounds__(256)
void k_kvred2(const bf16* __restrict__ part2, const float* __restrict__ part2Ks,
              bf16* __restrict__ KVb)
{
    const int b = blockIdx.x;
    const int n = b >> 3, h = b & 7;
    const int t = threadIdx.x;
    const int d = t >> 3, vg = t & 7;
    float s[4] = {};
    #pragma unroll
    for (int c8 = 0; c8 < 8; ++c8) {
        const bf16x4 p = *(const bf16x4*)&part2[(long)(c8 * 4 + n) * 8192 + h * 1024 + d * 32 + vg * 4];
        #pragma unroll
        for (int j = 0; j < 4; ++j) s[j] += b2f(p[j]);
    }
    bf16* dst = KVb + ((long)n * 8 + h) * 1536 + d * 48;
    bf16x4 o;
    #pragma unroll
    for (int j = 0; j < 4; ++j) o[j] = f2b(s[j]);
    *(bf16x4*)&dst[vg * 4] = o;
    if (vg == 0) {
        float ks = 0.f;
        #pragma unroll
        for (int c8 = 0; c8 < 8; ++c8) ks += part2Ks[(c8 * 4 + n) * 256 + h * 32 + d];
        short8 z0 = {};
        z0[0] = f2b(ks);
        *(short8*)&dst[32] = z0;
        short8 zz = {};
        *(short8*)&dst[40] = zz;
    }
}

// ---------------------------------------------------------------------------
// MEGA: Q-proj + feature-map + attention + merge-GEMM + LN1 (proven in R8).
// ---------------------------------------------------------------------------
__global__ __launch_bounds__(512)
void k_qaml(const bf16* __restrict__ xb, const bf16* __restrict__ WqT,
            const bf16* __restrict__ WmT, const bf16* __restrict__ KVb,
            const float* __restrict__ g, const float* __restrict__ b,
            bf16* __restrict__ msgln)
{
    __shared__ __attribute__((aligned(16))) bf16 Asm[64 * 64];
    __shared__ __attribute__((aligned(16))) bf16 Bsm[256 * 64];
    __shared__ __attribute__((aligned(16))) bf16 QM[64 * 264];
    __shared__ float lnS[4][64];
    __shared__ float lnQ[4][64];
    const int t = threadIdx.x, w = t >> 6, lane = t & 63;
    const int wm = w >> 2, wn = w & 3;
    const long row0 = (long)blockIdx.x * 64;
    const int n_b = (int)(row0 >> 13);
    const int lr = lane >> 3, lc = (lane & 7) * 8;
    const int lg = lane >> 4, l15 = lane & 15;

    {
        f32x4 acc[2][4] = {};
        for (int kt = 0; kt < 256; kt += 64) {
            async16(xb + (row0 + w * 8 + lr) * 256 + kt + lc, &Asm[w * 512]);
            #pragma unroll
            for (int i = 0; i < 4; ++i) {
                const int ch = i * 8 + w;
                async16(WqT + (long)(ch * 8 + lr) * 256 + kt + lc, &Bsm[ch * 512]);
            }
            __syncthreads();
            #pragma unroll
            for (int ks = 0; ks < 2; ++ks) {
                short8 a[2], bb[4];
                #pragma unroll
                for (int m = 0; m < 2; ++m)
                    a[m] = *(const short8*)&Asm[(wm*32 + m*16 + l15)*64 + ks*32 + lg*8];
                #pragma unroll
                for (int n = 0; n < 4; ++n)
                    bb[n] = *(const short8*)&Bsm[(wn*64 + n*16 + l15)*64 + ks*32 + lg*8];
                #pragma unroll
                for (int m = 0; m < 2; ++m)
                    #pragma unroll
                    for (int n = 0; n < 4; ++n)
                        acc[m][n] = __builtin_amdgcn_mfma_f32_16x16x32_bf16(a[m], bb[n], acc[m][n], 0, 0, 0);
            }
            __syncthreads();
        }
        #pragma unroll
        for (int m = 0; m < 2; ++m) {
            #pragma unroll
            for (int n = 0; n < 4; ++n) {
                #pragma unroll
                for (int r = 0; r < 4; ++r) {
                    const int row = wm * 32 + m * 16 + lg * 4 + r;
                    const int col = wn * 64 + n * 16 + l15;
                    float v = acc[m][n][r];
                    v = v > 0.f ? v + 1.f : __expf(v);
                    QM[row * 264 + col] = __float2bfloat16(v);
                }
            }
        }
    }
    __syncthreads();

    {
        const bf16* kvh = KVb + (long)n_b * 12288 + w * 1536;
        short8 b0, b1, bz;
        #pragma unroll
        for (int j = 0; j < 8; ++j) {
            const int drow = (lg * 8 + j) * 48;
            b0[j] = __builtin_bit_cast(short, kvh[drow + l15]);
            b1[j] = __builtin_bit_cast(short, kvh[drow + 16 + l15]);
            bz[j] = __builtin_bit_cast(short, kvh[drow + 32 + l15]);
        }
        f32x4 ra0[4], ra1[4];
        #pragma unroll
        for (int m2 = 0; m2 < 4; ++m2) {
            const short8 a = *(const short8*)&QM[(m2 * 16 + l15) * 264 + w * 32 + lg * 8];
            f32x4 a0 = {}, a1 = {}, az = {};
            a0 = __builtin_amdgcn_mfma_f32_16x16x32_bf16(a, b0, a0, 0, 0, 0);
            a1 = __builtin_amdgcn_mfma_f32_16x16x32_bf16(a, b1, a1, 0, 0, 0);
            az = __builtin_amdgcn_mfma_f32_16x16x32_bf16(a, bz, az, 0, 0, 0);
            #pragma unroll
            for (int r = 0; r < 4; ++r) {
                const float z   = __shfl(az[r], lane & 48);
                const float inv = 8192.f / (z + EPS_ATTN);
                ra0[m2][r] = a0[r] * inv;
                ra1[m2][r] = a1[r] * inv;
            }
        }
        __syncthreads();
        #pragma unroll
        for (int m2 = 0; m2 < 4; ++m2) {
            #pragma unroll
            for (int r = 0; r < 4; ++r) {
                const int row = m2 * 16 + lg * 4 + r;
                QM[row * 264 + w * 32 + l15]      = __float2bfloat16(ra0[m2][r]);
                QM[row * 264 + w * 32 + 16 + l15] = __float2bfloat16(ra1[m2][r]);
            }
        }
    }
    __syncthreads();

    f32x4 acc[2][4] = {};
    for (int kt = 0; kt < 256; kt += 64) {
        #pragma unroll
        for (int i = 0; i < 4; ++i) {
            const int ch = i * 8 + w;
            async16(WmT + (long)(ch * 8 + lr) * 256 + kt + lc, &Bsm[ch * 512]);
        }
        __syncthreads();
        #pragma unroll
        for (int ks = 0; ks < 2; ++ks) {
            short8 a[2], bb[4];
            #pragma unroll
            for (int m = 0; m < 2; ++m)
                a[m] = *(const short8*)&QM[(wm*32 + m*16 + l15) * 264 + kt + ks*32 + lg*8];
            #pragma unroll
            for (int n = 0; n < 4; ++n)
                bb[n] = *(const short8*)&Bsm[(wn*64 + n*16 + l15)*64 + ks*32 + lg*8];
            #pragma unroll
            for (int m = 0; m < 2; ++m)
                #pragma unroll
                for (int n = 0; n < 4; ++n)
                    acc[m][n] = __builtin_amdgcn_mfma_f32_16x16x32_bf16(a[m], bb[n], acc[m][n], 0, 0, 0);
        }
        __syncthreads();
    }

    #pragma unroll
    for (int m = 0; m < 2; ++m) {
        #pragma unroll
        for (int r = 0; r < 4; ++r) {
            float ls = 0.f, lq = 0.f;
            #pragma unroll
            for (int n = 0; n < 4; ++n) {
                const float v = acc[m][n][r];
                ls += v; lq += v * v;
            }
            #pragma unroll
            for (int o = 1; o < 16; o <<= 1) {
                ls += __shfl_xor(ls, o);
                lq += __shfl_xor(lq, o);
            }
            if (l15 == 0) {
                const int row = wm * 32 + m * 16 + lg * 4 + r;
                lnS[wn][row] = ls;
                lnQ[wn][row] = lq;
            }
        }
    }
    __syncthreads();

    float gv[4], bv[4];
    #pragma unroll
    for (int n = 0; n < 4; ++n) {
        const int col = wn * 64 + n * 16 + l15;
        gv[n] = g[col]; bv[n] = b[col];
    }
    #pragma unroll
    for (int m = 0; m < 2; ++m) {
        #pragma unroll
        for (int r = 0; r < 4; ++r) {
            const int row = wm * 32 + m * 16 + lg * 4 + r;
            const float S  = lnS[0][row] + lnS[1][row] + lnS[2][row] + lnS[3][row];
            const float Qq = lnQ[0][row] + lnQ[1][row] + lnQ[2][row] + lnQ[3][row];
            const float mean = S * (1.f / 256.f);
            const float var  = Qq * (1.f / 256.f) - mean * mean;
            const float rstd = rsqrtf(var + EPS_LN);
            const long grow = row0 + row;
            #pragma unroll
            for (int n = 0; n < 4; ++n) {
                const int col = wn * 64 + n * 16 + l15;
                const float y = (acc[m][n][r] - mean) * rstd * gv[n] + bv[n];
                msgln[grow * 256 + col] = __float2bfloat16(y);
            }
        }
    }
}

// ---------------------------------------------------------------------------
// W1 GEMM, 8-PHASE 256x256 schedule (T2+T3+T4+T5). t = relu([A0|A1] @ W1).
// M=32768, N=512, K=512. Grid (128,2) x 512 thr (8 waves, 2M x 4N).
// LDS 128KB: 2 K-tile buffers x {A 256x64 | B 256x64}. Swizzle: 16B slot
// ^= row&7 (pre-swizzled global_load_lds source + XOR'd ds_read).
// Per phase: {ds_reads, 1 half-tile stage, barrier, 16 MFMA (setprio), barrier}.
// vmcnt(4) at end of ph3/ph7 (counted, never 0 mid-loop); vmcnt(0) at ph3 of
// the last iteration. Derivation in session notes (buffer frees: B after ph1,
// A after ph3; stages ph2:B0 ph3:B1 ph4:A0 ph5:A1 of even buf, ph6/7+ph0'/1'
// of odd buf).
// ---------------------------------------------------------------------------
__global__ __launch_bounds__(512, 2)
void k_gemmW1_8p(const bf16* __restrict__ A0, const bf16* __restrict__ A1,
                 const bf16* __restrict__ BT, bf16* __restrict__ C)
{
    __shared__ __attribute__((aligned(16))) bf16 S[65536];   // 128 KB
    const int t = threadIdx.x, w = t >> 6, lane = t & 63;
    const int wm = w >> 2, wn = w & 3;
    const int lg = lane >> 4, l15 = lane & 15;
    const int orig = blockIdx.y * gridDim.x + blockIdx.x;    // 0..255
    const int swz  = (orig & 7) * 32 + (orig >> 3);          // bijective XCD
    const long row0 = (long)(swz >> 1) * 256;
    const long col0 = (long)(swz & 1) * 256;

    f32x4 acc[8][4] = {};
    short8 av[4], bv0[4], bv1[4];

    // stage one half-tile (2 global_load_lds per thread) with pre-swizzled src
    auto stageA = [&](int tile, int half) {
        if (tile >= 8) return;
        const bf16* Asrc = (tile < 4) ? A0 : A1;
        const int kbase = (tile & 3) * 64;
        #pragma unroll
        for (int i = 0; i < 2; ++i) {
            const int cbase = i * 512 + w * 64;
            const int c = cbase + lane;
            const int srow = c >> 3;                       // 0..127
            const int lcol = 8 * ((c & 7) ^ (srow & 7));   // swizzled source
            async16(Asrc + (row0 + half * 128 + srow) * 256 + kbase + lcol,
                    &S[(tile & 1) * 32768 + half * 8192 + cbase * 8]);
        }
    };
    auto stageB = [&](int tile, int half) {
        if (tile >= 8) return;
        const int kbase = tile * 64;
        #pragma unroll
        for (int i = 0; i < 2; ++i) {
            const int cbase = i * 512 + w * 64;
            const int c = cbase + lane;
            const int srow = c >> 3;
            const int lcol = 8 * ((c & 7) ^ (srow & 7));
            async16(BT + (col0 + half * 128 + srow) * 512 + kbase + lcol,
                    &S[(tile & 1) * 32768 + 16384 + half * 8192 + cbase * 8]);
        }
    };

#define RD_A(BUF, MH, KS) do { _Pragma("unroll")                               \
    for (int m_ = 0; m_ < 4; ++m_) {                                           \
        const int row_ = wm * 128 + (MH) * 64 + m_ * 16 + l15;                 \
        av[m_] = *(const short8*)&S[(BUF) * 32768 + row_ * 64 +                \
                 (((KS) * 32 + lg * 8) ^ ((row_ & 7) << 3))]; } } while (0)

#define RD_B(BUF, KS, BV) do { _Pragma("unroll")                               \
    for (int n_ = 0; n_ < 4; ++n_) {                                           \
        const int row_ = wn * 64 + n_ * 16 + l15;                              \
        (BV)[n_] = *(const short8*)&S[(BUF) * 32768 + 16384 + row_ * 64 +      \
                 (((KS) * 32 + lg * 8) ^ ((row_ & 7) << 3))]; } } while (0)

#define DO_MFMA(MH, BV) do { __builtin_amdgcn_s_setprio(1); _Pragma("unroll")  \
    for (int m_ = 0; m_ < 4; ++m_) { _Pragma("unroll")                         \
        for (int n_ = 0; n_ < 4; ++n_)                                         \
            acc[(MH) * 4 + m_][n_] = __builtin_amdgcn_mfma_f32_16x16x32_bf16(  \
                av[m_], (BV)[n_], acc[(MH) * 4 + m_][n_], 0, 0, 0); }          \
    __builtin_amdgcn_s_setprio(0); } while (0)

#define BAR() __builtin_amdgcn_s_barrier()

    // prologue: tile0 {B0,B1,A0,A1} + tile1 {B0,B1} = 12 loads/thread
    stageB(0, 0); stageB(0, 1); stageA(0, 0); stageA(0, 1);
    stageB(1, 0); stageB(1, 1);
    asm volatile("s_waitcnt vmcnt(4)" ::: "memory");   // tile0 landed
    BAR();

    for (int it = 0; it < 4; ++it) {
        const int T1 = 2 * it + 1;
        // ---- ph0: buf0 (mh0,ks0) ----
        RD_B(0, 0, bv0); RD_A(0, 0, 0); stageA(T1, 0);
        BAR(); DO_MFMA(0, bv0); BAR();
        // ---- ph1: buf0 (mh0,ks1) ----
        RD_B(0, 1, bv1); RD_A(0, 0, 1); stageA(T1, 1);
        BAR(); DO_MFMA(0, bv1); BAR();
        // ---- ph2: buf0 (mh1,ks0) ----
        RD_A(0, 1, 0); stageB(T1 + 1, 0);
        BAR(); DO_MFMA(1, bv0); BAR();
        // ---- ph3: buf0 (mh1,ks1) ----
        RD_A(0, 1, 1); stageB(T1 + 1, 1);
        BAR(); DO_MFMA(1, bv1);
        if (it == 3) asm volatile("s_waitcnt vmcnt(0)" ::: "memory");
        else         asm volatile("s_waitcnt vmcnt(4)" ::: "memory");
        BAR();
        // ---- ph4: buf1 (mh0,ks0) ----
        RD_B(1, 0, bv0); RD_A(1, 0, 0); stageA(T1 + 1, 0);
        BAR(); DO_MFMA(0, bv0); BAR();
        // ---- ph5: buf1 (mh0,ks1) ----
        RD_B(1, 1, bv1); RD_A(1, 0, 1); stageA(T1 + 1, 1);
        BAR(); DO_MFMA(0, bv1); BAR();
        // ---- ph6: buf1 (mh1,ks0) ----
        RD_A(1, 1, 0); stageB(T1 + 2, 0);
        BAR(); DO_MFMA(1, bv0); BAR();
        // ---- ph7: buf1 (mh1,ks1) ----
        RD_A(1, 1, 1); stageB(T1 + 2, 1);
        BAR(); DO_MFMA(1, bv1);
        if (it < 3) asm volatile("s_waitcnt vmcnt(4)" ::: "memory");
        BAR();
    }

    // epilogue: relu + store
    #pragma unroll
    for (int mi = 0; mi < 8; ++mi) {
        #pragma unroll
        for (int n = 0; n < 4; ++n) {
            #pragma unroll
            for (int r = 0; r < 4; ++r) {
                const long row = row0 + wm * 128 + mi * 16 + lg * 4 + r;
                const long col = col0 + wn * 64 + n * 16 + l15;
                const float v = acc[mi][n][r];
                C[row * 512 + col] = __float2bfloat16(v > 0.f ? v : 0.f);
            }
        }
    }
#undef RD_A
#undef RD_B
#undef DO_MFMA
#undef BAR
}

// ---------------------------------------------------------------------------
// Fused GEMM(K=512) + LN2 + residual: out = fp32 x + LN(A@B) (proven R9).
// ---------------------------------------------------------------------------
__global__ __launch_bounds__(512)
void k_gemm_ln2(const bf16* __restrict__ A, const bf16* __restrict__ BT,
                const float* __restrict__ g, const float* __restrict__ b,
                const float* __restrict__ xres, float* __restrict__ out)
{
    __shared__ __attribute__((aligned(16))) bf16 Asm[64 * 64];
    __shared__ __attribute__((aligned(16))) bf16 Bsm[256 * 64];
    __shared__ float lnS[4][64];
    __shared__ float lnQ[4][64];
    const int t = threadIdx.x, w = t >> 6, lane = t & 63;
    const int wm = w >> 2, wn = w & 3;
    const long row0 = (long)blockIdx.x * 64;
    const int lr = lane >> 3, lc = (lane & 7) * 8;
    const int lg = lane >> 4, l15 = lane & 15;

    f32x4 acc[2][4] = {};

    for (int kt = 0; kt < 512; kt += 64) {
        async16(A + (row0 + w * 8 + lr) * 512 + kt + lc, &Asm[w * 512]);
        #pragma unroll
        for (int i = 0; i < 4; ++i) {
            const int ch = i * 8 + w;
            async16(BT + (long)(ch * 8 + lr) * 512 + kt + lc, &Bsm[ch * 512]);
        }
        __syncthreads();
        #pragma unroll
        for (int ks = 0; ks < 2; ++ks) {
            short8 a[2], bb[4];
            #pragma unroll
            for (int m = 0; m < 2; ++m)
                a[m] = *(const short8*)&Asm[(wm*32 + m*16 + l15)*64 + ks*32 + lg*8];
            #pragma unroll
            for (int n = 0; n < 4; ++n)
                bb[n] = *(const short8*)&Bsm[(wn*64 + n*16 + l15)*64 + ks*32 + lg*8];
            #pragma unroll
            for (int m = 0; m < 2; ++m)
                #pragma unroll
                for (int n = 0; n < 4; ++n)
                    acc[m][n] = __builtin_amdgcn_mfma_f32_16x16x32_bf16(a[m], bb[n], acc[m][n], 0, 0, 0);
        }
        __syncthreads();
    }

    #pragma unroll
    for (int m = 0; m < 2; ++m) {
        #pragma unroll
        for (int r = 0; r < 4; ++r) {
            float ls = 0.f, lq = 0.f;
            #pragma unroll
            for (int n = 0; n < 4; ++n) {
                const float v = acc[m][n][r];
                ls += v; lq += v * v;
            }
            #pragma unroll
            for (int o = 1; o < 16; o <<= 1) {
                ls += __shfl_xor(ls, o);
                lq += __shfl_xor(lq, o);
            }
            if (l15 == 0) {
                const int row = wm * 32 + m * 16 + lg * 4 + r;
                lnS[wn][row] = ls;
                lnQ[wn][row] = lq;
            }
        }
    }
    __syncthreads();

    float gv[4], bv[4];
    #pragma unroll
    for (int n = 0; n < 4; ++n) {
        const int col = wn * 64 + n * 16 + l15;
        gv[n] = g[col]; bv[n] = b[col];
    }
    #pragma unroll
    for (int m = 0; m < 2; ++m) {
        #pragma unroll
        for (int r = 0; r < 4; ++r) {
            const int row = wm * 32 + m * 16 + lg * 4 + r;
            const float S  = lnS[0][row] + lnS[1][row] + lnS[2][row] + lnS[3][row];
            const float Qq = lnQ[0][row] + lnQ[1][row] + lnQ[2][row] + lnQ[3][row];
            const float mean = S * (1.f / 256.f);
            const float var  = Qq * (1.f / 256.f) - mean * mean;
            const float rstd = rsqrtf(var + EPS_LN);
            const long grow = row0 + row;
            #pragma unroll
            for (int n = 0; n < 4; ++n) {
                const int col = wn * 64 + n * 16 + l15;
                const float y = (acc[m][n][r] - mean) * rstd * gv[n] + bv[n];
                out[grow * 256 + col] = xres[grow * 256 + col] + y;
            }
        }
    }
}

// ---------------------------------------------------------------------------
extern "C" void kernel_launch(void* const* d_in, const int* in_sizes, int n_in,
                              void* d_out, int out_size, void* d_ws, size_t ws_size,
                              hipStream_t stream)
{
    const float* x      = (const float*)d_in[0];
    const float* source = (const float*)d_in[1];
    const float* Wq     = (const float*)d_in[2];
    const float* Wk     = (const float*)d_in[3];
    const float* Wv     = (const float*)d_in[4];
    const float* Wm     = (const float*)d_in[5];
    const float* W1     = (const float*)d_in[6];
    const float* W2     = (const float*)d_in[7];
    const float* g1     = (const float*)d_in[8];
    const float* b1     = (const float*)d_in[9];
    const float* g2     = (const float*)d_in[10];
    const float* b2     = (const float*)d_in[11];
    float* out = (float*)d_out;

    const size_t U = 32768ull * 256ull;
    char* w = (char*)d_ws;

    // slots (16 MB each); lifetimes:
    bf16* x_bf  = (bf16*)(w + 0 * U * 2);   // alive through W1 gemm
    bf16* s_bf  = (bf16*)(w + 1 * U * 2);   // dead after k_kvproj
    bf16* msgln = (bf16*)(w + 2 * U * 2);   // qaml out, alive through W1
    bf16* t_bf  = (bf16*)(w + 3 * U * 2);   // slots 3-4 ([32768,512])

    char* wx = w + 7 * U * 2;
    bf16* WqT = (bf16*)wx; wx += 65536 * 2;
    bf16* WkT = (bf16*)wx; wx += 65536 * 2;   // contiguous with WvT -> [512][256]
    bf16* WvT = (bf16*)wx; wx += 65536 * 2;
    bf16* WmT = (bf16*)wx; wx += 65536 * 2;
    bf16* W1T = (bf16*)wx; wx += 262144 * 2;
    bf16* W2T = (bf16*)wx; wx += 131072 * 2;
    bf16* partKV = (bf16*)wx; wx += 2097152 * 2;   // 256 cid x 8192
    float* partKs = (float*)wx; wx += 65536 * 4;   // 256 cid x 256
    bf16* part2  = (bf16*)wx; wx += 262144 * 2;    // 8 x 4 x 8192
    float* part2Ks = (float*)wx; wx += 8192 * 4;   // 8 x 4 x 256
    bf16* KVb    = (bf16*)wx; wx += 49152 * 2;     // [n][h][32][48]

    const dim3 blk(256);

    // 1) prep: converts + all weight transposes (one launch)
    k_prep<<<8352, blk, 0, stream>>>(x, source, x_bf, s_bf,
                                     Wq, Wk, Wv, Wm, W1, W2,
                                     WqT, WkT, WvT, WmT, W1T, W2T);

    // 2) FUSED K/V projection + partial KV/Ksum
    k_kvproj<<<dim3(256, 2), dim3(512), 0, stream>>>(s_bf, WkT, partKV, partKs,
                                                     1.f / 8192.f);

    // 3) reduce partials -> KVaug
    k_kvred1<<<256, blk, 0, stream>>>(partKV, partKs, part2, part2Ks);
    k_kvred2<<<32, blk, 0, stream>>>(part2, part2Ks, KVb);

    // 4) MEGA: Q-proj + attn + merge + LN1 -> msgln
    k_qaml<<<512, dim3(512), 0, stream>>>(x_bf, WqT, WmT, KVb, g1, b1, msgln);

    // 5) MLP: t = relu([x_bf|msgln]@W1) via 8-PHASE; out = x + LN2(t@W2)
    k_gemmW1_8p<<<dim3(128, 2), dim3(512), 0, stream>>>(x_bf, msgln, W1T, t_bf);
    k_gemm_ln2<<<512, dim3(512), 0, stream>>>(t_bf, W2T, g2, b2, x, out);
}

// Round 12
// 131.295 us; speedup vs baseline: 1.1408x; 1.0009x over previous
//
#include <hip/hip_runtime.h>
#include <hip/hip_bf16.h>
#include <stdint.h>

typedef __hip_bfloat16 bf16;
typedef __attribute__((ext_vector_type(8))) short short8;
typedef __attribute__((ext_vector_type(4))) short bf16x4;
typedef __attribute__((ext_vector_type(4))) float f32x4;

#define EPS_ATTN 1e-6f
#define EPS_LN   1e-5f

__device__ __forceinline__ float b2f(short s) {
    return __builtin_bit_cast(float, (unsigned)((unsigned short)s) << 16);
}
__device__ __forceinline__ short f2b(float f) {
    return __builtin_bit_cast(short, __float2bfloat16(f));
}

// ---------------------------------------------------------------------------
// async global->LDS, 16B per lane. LDS dest = wave-uniform base + lane*16.
// ---------------------------------------------------------------------------
__device__ __forceinline__ void async16(const void* g, void* l) {
    __builtin_amdgcn_global_load_lds(
        (const __attribute__((address_space(1))) void*)g,
        (__attribute__((address_space(3))) void*)l,
        16, 0, 0);
}

// ---------------------------------------------------------------------------
// Prep: fp32->bf16 converts (x, source) + all 6 weight transposes, ONE launch.
// ---------------------------------------------------------------------------
__global__ __launch_bounds__(256)
void k_prep(const float* __restrict__ x, const float* __restrict__ src,
            bf16* __restrict__ x_bf, bf16* __restrict__ s_bf,
            const float* __restrict__ Wq, const float* __restrict__ Wk,
            const float* __restrict__ Wv, const float* __restrict__ Wm,
            const float* __restrict__ W1, const float* __restrict__ W2,
            bf16* __restrict__ WqT, bf16* __restrict__ WkT,
            bf16* __restrict__ WvT, bf16* __restrict__ WmT,
            bf16* __restrict__ W1T, bf16* __restrict__ W2T)
{
    __shared__ float tile[64][65];
    const int blk = blockIdx.x;
    if (blk < 8192) {
        const float* in = (blk < 4096) ? x : src;
        bf16* out       = (blk < 4096) ? x_bf : s_bf;
        const long id = (long)(blk & 4095) * 256 + threadIdx.x;
        const float4 a = ((const float4*)in)[id * 2];
        const float4 b = ((const float4*)in)[id * 2 + 1];
        short8 o;
        o[0] = f2b(a.x); o[1] = f2b(a.y); o[2] = f2b(a.z); o[3] = f2b(a.w);
        o[4] = f2b(b.x); o[5] = f2b(b.y); o[6] = f2b(b.z); o[7] = f2b(b.w);
        ((short8*)out)[id] = o;
        return;
    }
    const int b = blk - 8192;
    const float* W; bf16* WT; int K, N, local;
    if      (b < 16)  { W = Wq; WT = WqT; K = 256; N = 256; local = b; }
    else if (b < 32)  { W = Wk; WT = WkT; K = 256; N = 256; local = b - 16; }
    else if (b < 48)  { W = Wv; WT = WvT; K = 256; N = 256; local = b - 32; }
    else if (b < 64)  { W = Wm; WT = WmT; K = 256; N = 256; local = b - 48; }
    else if (b < 128) { W = W1; WT = W1T; K = 512; N = 512; local = b - 64; }
    else              { W = W2; WT = W2T; K = 512; N = 256; local = b - 128; }
    const int tk = K / 64;
    const int k0 = (local % tk) * 64, n0 = (local / tk) * 64;
    const int ty = threadIdx.x >> 4, tx = threadIdx.x & 15;
    #pragma unroll
    for (int i = 0; i < 4; ++i) {
        const int k = ty + i * 16;
        const float4 v = *(const float4*)&W[(long)(k0 + k) * N + n0 + tx * 4];
        tile[k][tx * 4 + 0] = v.x; tile[k][tx * 4 + 1] = v.y;
        tile[k][tx * 4 + 2] = v.z; tile[k][tx * 4 + 3] = v.w;
    }
    __syncthreads();
    #pragma unroll
    for (int i = 0; i < 4; ++i) {
        const int n = ty + i * 16;
        bf16x4 o;
        #pragma unroll
        for (int j = 0; j < 4; ++j) o[j] = f2b(tile[tx * 4 + j][n]);
        *(bf16x4*)&WT[(long)(n0 + n) * K + k0 + tx * 4] = o;
    }
}

// ---------------------------------------------------------------------------
// FUSED K/V projection + feature-map + partial-KV/Ksum (proven in R9).
// ---------------------------------------------------------------------------
__global__ __launch_bounds__(512)
void k_kvproj(const bf16* __restrict__ A, const bf16* __restrict__ BT,
              bf16* __restrict__ partKV, float* __restrict__ partKs,
              float escale)
{
    __shared__ __attribute__((aligned(16))) bf16 S[32768];   // 64 KB union
    bf16* Asm = S;
    bf16* Bsm = S + 8192;
    bf16* KT  = S;
    bf16* VT  = S + 16384;

    const int t = threadIdx.x, w = t >> 6, lane = t & 63;
    const int wm = w >> 2, wn = w & 3;
    const int flat = blockIdx.y * gridDim.x + blockIdx.x;   // 0..511
    const int swz  = (flat & 7) * 64 + (flat >> 3);         // bijective, XCD
    const int cid  = swz >> 1;
    const int hh   = swz & 1;
    const long row0 = (long)cid * 128;
    const int lr = lane >> 3, lc = (lane & 7) * 8;
    const int lg = lane >> 4, l15 = lane & 15;

    f32x4 acc[4][4] = {};

    for (int kt = 0; kt < 256; kt += 64) {
        #pragma unroll
        for (int i = 0; i < 2; ++i) {
            const int g = w * 2 + i;
            async16(A + (row0 + g * 8 + lr) * 256 + kt + lc, &Asm[g * 512]);
        }
        #pragma unroll
        for (int i = 0; i < 4; ++i) {
            const int g = w * 4 + i;
            const long brow = (g < 16)
                ? (long)(hh * 128 + g * 8 + lr)
                : (long)(256 + hh * 128 + (g - 16) * 8 + lr);
            async16(BT + brow * 256 + kt + lc, &Bsm[g * 512]);
        }
        __syncthreads();
        #pragma unroll
        for (int ks = 0; ks < 2; ++ks) {
            short8 a[4], b[4];
            #pragma unroll
            for (int m = 0; m < 4; ++m)
                a[m] = *(const short8*)&Asm[(wm*64 + m*16 + l15)*64 + ks*32 + lg*8];
            #pragma unroll
            for (int n = 0; n < 4; ++n)
                b[n] = *(const short8*)&Bsm[(wn*64 + n*16 + l15)*64 + ks*32 + lg*8];
            #pragma unroll
            for (int m = 0; m < 4; ++m)
                #pragma unroll
                for (int n = 0; n < 4; ++n)
                    acc[m][n] = __builtin_amdgcn_mfma_f32_16x16x32_bf16(a[m], b[n], acc[m][n], 0, 0, 0);
        }
        __syncthreads();
    }

    const bool isK = wn < 2;
    bf16* tile = isK ? KT : VT;
    #pragma unroll
    for (int m = 0; m < 4; ++m) {
        #pragma unroll
        for (int n = 0; n < 4; ++n) {
            #pragma unroll
            for (int r = 0; r < 4; ++r) {
                const int row = wm * 64 + m * 16 + lg * 4 + r;
                const int col = (wn & 1) * 64 + n * 16 + l15;
                float v = acc[m][n][r];
                if (isK) v = v > 0.f ? v + 1.f : __expf(v);
                else     v *= escale;
                tile[row * 128 + col] = __float2bfloat16(v);
            }
        }
    }
    __syncthreads();

    const int h_l = t >> 7;
    const int d   = (t & 127) >> 2;
    const int vg  = t & 3;
    float a2[8] = {};
    float ks = 0.f;
    #pragma unroll 4
    for (int row = 0; row < 128; ++row) {
        const float kd = __bfloat162float(KT[row * 128 + h_l * 32 + d]);
        ks += kd;
        const short8 vv = *(const short8*)&VT[row * 128 + h_l * 32 + vg * 8];
        #pragma unroll
        for (int u = 0; u < 8; ++u) a2[u] += kd * b2f(vv[u]);
    }
    short8 o;
    #pragma unroll
    for (int u = 0; u < 8; ++u) o[u] = f2b(a2[u]);
    *(short8*)&partKV[(long)cid * 8192 + (hh * 4 + h_l) * 1024 + d * 32 + vg * 8] = o;
    if (vg == 0) partKs[cid * 256 + (hh * 4 + h_l) * 32 + d] = ks;
}

// ---------------------------------------------------------------------------
// KV reduce stage 1: 64 chunks/batch -> 8 partials.
// ---------------------------------------------------------------------------
__global__ __launch_bounds__(256)
void k_kvred1(const bf16* __restrict__ partKV, const float* __restrict__ partKs,
              bf16* __restrict__ part2, float* __restrict__ part2Ks)
{
    const int bid = blockIdx.x;
    const int c8 = bid & 7, h = (bid >> 3) & 7, n = bid >> 6;
    const int t = threadIdx.x;
    const int d = t >> 3, vg = t & 7;
    float s[4] = {};
    #pragma unroll
    for (int j = 0; j < 8; ++j) {
        const int cid = n * 64 + c8 * 8 + j;
        const bf16x4 p = *(const bf16x4*)&partKV[(long)cid * 8192 + h * 1024 + d * 32 + vg * 4];
        #pragma unroll
        for (int jj = 0; jj < 4; ++jj) s[jj] += b2f(p[jj]);
    }
    bf16x4 o;
    #pragma unroll
    for (int jj = 0; jj < 4; ++jj) o[jj] = f2b(s[jj]);
    *(bf16x4*)&part2[(long)(c8 * 4 + n) * 8192 + h * 1024 + d * 32 + vg * 4] = o;
    if (vg == 0) {
        float ks = 0.f;
        #pragma unroll
        for (int j = 0; j < 8; ++j) {
            const int cid = n * 64 + c8 * 8 + j;
            ks += partKs[cid * 256 + h * 32 + d];
        }
        part2Ks[(c8 * 4 + n) * 256 + h * 32 + d] = ks;
    }
}

// ---------------------------------------------------------------------------
// KV reduce stage 2: 8 partials -> KVaug bf16 [n][h][32][48] (col 32 = Ksum)
// ---------------------------------------------------------------------------
__global__ __launch_bounds__(256)
void k_kvred2(const bf16* __restrict__ part2, const float* __restrict__ part2Ks,
              bf16* __restrict__ KVb)
{
    const int b = blockIdx.x;
    const int n = b >> 3, h = b & 7;
    const int t = threadIdx.x;
    const int d = t >> 3, vg = t & 7;
    float s[4] = {};
    #pragma unroll
    for (int c8 = 0; c8 < 8; ++c8) {
        const bf16x4 p = *(const bf16x4*)&part2[(long)(c8 * 4 + n) * 8192 + h * 1024 + d * 32 + vg * 4];
        #pragma unroll
        for (int j = 0; j < 4; ++j) s[j] += b2f(p[j]);
    }
    bf16* dst = KVb + ((long)n * 8 + h) * 1536 + d * 48;
    bf16x4 o;
    #pragma unroll
    for (int j = 0; j < 4; ++j) o[j] = f2b(s[j]);
    *(bf16x4*)&dst[vg * 4] = o;
    if (vg == 0) {
        float ks = 0.f;
        #pragma unroll
        for (int c8 = 0; c8 < 8; ++c8) ks += part2Ks[(c8 * 4 + n) * 256 + h * 32 + d];
        short8 z0 = {};
        z0[0] = f2b(ks);
        *(short8*)&dst[32] = z0;
        short8 zz = {};
        *(short8*)&dst[40] = zz;
    }
}

// ---------------------------------------------------------------------------
// MEGA: Q-proj + feature-map + attention + merge-GEMM + LN1 (proven in R8).
// ---------------------------------------------------------------------------
__global__ __launch_bounds__(512)
void k_qaml(const bf16* __restrict__ xb, const bf16* __restrict__ WqT,
            const bf16* __restrict__ WmT, const bf16* __restrict__ KVb,
            const float* __restrict__ g, const float* __restrict__ b,
            bf16* __restrict__ msgln)
{
    __shared__ __attribute__((aligned(16))) bf16 Asm[64 * 64];
    __shared__ __attribute__((aligned(16))) bf16 Bsm[256 * 64];
    __shared__ __attribute__((aligned(16))) bf16 QM[64 * 264];
    __shared__ float lnS[4][64];
    __shared__ float lnQ[4][64];
    const int t = threadIdx.x, w = t >> 6, lane = t & 63;
    const int wm = w >> 2, wn = w & 3;
    const long row0 = (long)blockIdx.x * 64;
    const int n_b = (int)(row0 >> 13);
    const int lr = lane >> 3, lc = (lane & 7) * 8;
    const int lg = lane >> 4, l15 = lane & 15;

    {
        f32x4 acc[2][4] = {};
        for (int kt = 0; kt < 256; kt += 64) {
            async16(xb + (row0 + w * 8 + lr) * 256 + kt + lc, &Asm[w * 512]);
            #pragma unroll
            for (int i = 0; i < 4; ++i) {
                const int ch = i * 8 + w;
                async16(WqT + (long)(ch * 8 + lr) * 256 + kt + lc, &Bsm[ch * 512]);
            }
            __syncthreads();
            #pragma unroll
            for (int ks = 0; ks < 2; ++ks) {
                short8 a[2], bb[4];
                #pragma unroll
                for (int m = 0; m < 2; ++m)
                    a[m] = *(const short8*)&Asm[(wm*32 + m*16 + l15)*64 + ks*32 + lg*8];
                #pragma unroll
                for (int n = 0; n < 4; ++n)
                    bb[n] = *(const short8*)&Bsm[(wn*64 + n*16 + l15)*64 + ks*32 + lg*8];
                #pragma unroll
                for (int m = 0; m < 2; ++m)
                    #pragma unroll
                    for (int n = 0; n < 4; ++n)
                        acc[m][n] = __builtin_amdgcn_mfma_f32_16x16x32_bf16(a[m], bb[n], acc[m][n], 0, 0, 0);
            }
            __syncthreads();
        }
        #pragma unroll
        for (int m = 0; m < 2; ++m) {
            #pragma unroll
            for (int n = 0; n < 4; ++n) {
                #pragma unroll
                for (int r = 0; r < 4; ++r) {
                    const int row = wm * 32 + m * 16 + lg * 4 + r;
                    const int col = wn * 64 + n * 16 + l15;
                    float v = acc[m][n][r];
                    v = v > 0.f ? v + 1.f : __expf(v);
                    QM[row * 264 + col] = __float2bfloat16(v);
                }
            }
        }
    }
    __syncthreads();

    {
        const bf16* kvh = KVb + (long)n_b * 12288 + w * 1536;
        short8 b0, b1, bz;
        #pragma unroll
        for (int j = 0; j < 8; ++j) {
            const int drow = (lg * 8 + j) * 48;
            b0[j] = __builtin_bit_cast(short, kvh[drow + l15]);
            b1[j] = __builtin_bit_cast(short, kvh[drow + 16 + l15]);
            bz[j] = __builtin_bit_cast(short, kvh[drow + 32 + l15]);
        }
        f32x4 ra0[4], ra1[4];
        #pragma unroll
        for (int m2 = 0; m2 < 4; ++m2) {
            const short8 a = *(const short8*)&QM[(m2 * 16 + l15) * 264 + w * 32 + lg * 8];
            f32x4 a0 = {}, a1 = {}, az = {};
            a0 = __builtin_amdgcn_mfma_f32_16x16x32_bf16(a, b0, a0, 0, 0, 0);
            a1 = __builtin_amdgcn_mfma_f32_16x16x32_bf16(a, b1, a1, 0, 0, 0);
            az = __builtin_amdgcn_mfma_f32_16x16x32_bf16(a, bz, az, 0, 0, 0);
            #pragma unroll
            for (int r = 0; r < 4; ++r) {
                const float z   = __shfl(az[r], lane & 48);
                const float inv = 8192.f / (z + EPS_ATTN);
                ra0[m2][r] = a0[r] * inv;
                ra1[m2][r] = a1[r] * inv;
            }
        }
        __syncthreads();
        #pragma unroll
        for (int m2 = 0; m2 < 4; ++m2) {
            #pragma unroll
            for (int r = 0; r < 4; ++r) {
                const int row = m2 * 16 + lg * 4 + r;
                QM[row * 264 + w * 32 + l15]      = __float2bfloat16(ra0[m2][r]);
                QM[row * 264 + w * 32 + 16 + l15] = __float2bfloat16(ra1[m2][r]);
            }
        }
    }
    __syncthreads();

    f32x4 acc[2][4] = {};
    for (int kt = 0; kt < 256; kt += 64) {
        #pragma unroll
        for (int i = 0; i < 4; ++i) {
            const int ch = i * 8 + w;
            async16(WmT + (long)(ch * 8 + lr) * 256 + kt + lc, &Bsm[ch * 512]);
        }
        __syncthreads();
        #pragma unroll
        for (int ks = 0; ks < 2; ++ks) {
            short8 a[2], bb[4];
            #pragma unroll
            for (int m = 0; m < 2; ++m)
                a[m] = *(const short8*)&QM[(wm*32 + m*16 + l15) * 264 + kt + ks*32 + lg*8];
            #pragma unroll
            for (int n = 0; n < 4; ++n)
                bb[n] = *(const short8*)&Bsm[(wn*64 + n*16 + l15)*64 + ks*32 + lg*8];
            #pragma unroll
            for (int m = 0; m < 2; ++m)
                #pragma unroll
                for (int n = 0; n < 4; ++n)
                    acc[m][n] = __builtin_amdgcn_mfma_f32_16x16x32_bf16(a[m], bb[n], acc[m][n], 0, 0, 0);
        }
        __syncthreads();
    }

    #pragma unroll
    for (int m = 0; m < 2; ++m) {
        #pragma unroll
        for (int r = 0; r < 4; ++r) {
            float ls = 0.f, lq = 0.f;
            #pragma unroll
            for (int n = 0; n < 4; ++n) {
                const float v = acc[m][n][r];
                ls += v; lq += v * v;
            }
            #pragma unroll
            for (int o = 1; o < 16; o <<= 1) {
                ls += __shfl_xor(ls, o);
                lq += __shfl_xor(lq, o);
            }
            if (l15 == 0) {
                const int row = wm * 32 + m * 16 + lg * 4 + r;
                lnS[wn][row] = ls;
                lnQ[wn][row] = lq;
            }
        }
    }
    __syncthreads();

    float gv[4], bv[4];
    #pragma unroll
    for (int n = 0; n < 4; ++n) {
        const int col = wn * 64 + n * 16 + l15;
        gv[n] = g[col]; bv[n] = b[col];
    }
    #pragma unroll
    for (int m = 0; m < 2; ++m) {
        #pragma unroll
        for (int r = 0; r < 4; ++r) {
            const int row = wm * 32 + m * 16 + lg * 4 + r;
            const float S  = lnS[0][row] + lnS[1][row] + lnS[2][row] + lnS[3][row];
            const float Qq = lnQ[0][row] + lnQ[1][row] + lnQ[2][row] + lnQ[3][row];
            const float mean = S * (1.f / 256.f);
            const float var  = Qq * (1.f / 256.f) - mean * mean;
            const float rstd = rsqrtf(var + EPS_LN);
            const long grow = row0 + row;
            #pragma unroll
            for (int n = 0; n < 4; ++n) {
                const int col = wn * 64 + n * 16 + l15;
                const float y = (acc[m][n][r] - mean) * rstd * gv[n] + bv[n];
                msgln[grow * 256 + col] = __float2bfloat16(y);
            }
        }
    }
}

// ---------------------------------------------------------------------------
// W1 GEMM, 8-PHASE 256x256 schedule (proven in R11). t = relu([A0|A1] @ W1).
// ---------------------------------------------------------------------------
__global__ __launch_bounds__(512, 2)
void k_gemmW1_8p(const bf16* __restrict__ A0, const bf16* __restrict__ A1,
                 const bf16* __restrict__ BT, bf16* __restrict__ C)
{
    __shared__ __attribute__((aligned(16))) bf16 S[65536];   // 128 KB
    const int t = threadIdx.x, w = t >> 6, lane = t & 63;
    const int wm = w >> 2, wn = w & 3;
    const int lg = lane >> 4, l15 = lane & 15;
    const int orig = blockIdx.y * gridDim.x + blockIdx.x;    // 0..255
    const int swz  = (orig & 7) * 32 + (orig >> 3);          // bijective XCD
    const long row0 = (long)(swz >> 1) * 256;
    const long col0 = (long)(swz & 1) * 256;

    f32x4 acc[8][4] = {};
    short8 av[4], bv0[4], bv1[4];

    auto stageA = [&](int tile, int half) {
        if (tile >= 8) return;
        const bf16* Asrc = (tile < 4) ? A0 : A1;
        const int kbase = (tile & 3) * 64;
        #pragma unroll
        for (int i = 0; i < 2; ++i) {
            const int cbase = i * 512 + w * 64;
            const int c = cbase + lane;
            const int srow = c >> 3;
            const int lcol = 8 * ((c & 7) ^ (srow & 7));
            async16(Asrc + (row0 + half * 128 + srow) * 256 + kbase + lcol,
                    &S[(tile & 1) * 32768 + half * 8192 + cbase * 8]);
        }
    };
    auto stageB = [&](int tile, int half) {
        if (tile >= 8) return;
        const int kbase = tile * 64;
        #pragma unroll
        for (int i = 0; i < 2; ++i) {
            const int cbase = i * 512 + w * 64;
            const int c = cbase + lane;
            const int srow = c >> 3;
            const int lcol = 8 * ((c & 7) ^ (srow & 7));
            async16(BT + (col0 + half * 128 + srow) * 512 + kbase + lcol,
                    &S[(tile & 1) * 32768 + 16384 + half * 8192 + cbase * 8]);
        }
    };

#define RD_A(BUF, MH, KS) do { _Pragma("unroll")                               \
    for (int m_ = 0; m_ < 4; ++m_) {                                           \
        const int row_ = wm * 128 + (MH) * 64 + m_ * 16 + l15;                 \
        av[m_] = *(const short8*)&S[(BUF) * 32768 + row_ * 64 +                \
                 (((KS) * 32 + lg * 8) ^ ((row_ & 7) << 3))]; } } while (0)

#define RD_B(BUF, KS, BV) do { _Pragma("unroll")                               \
    for (int n_ = 0; n_ < 4; ++n_) {                                           \
        const int row_ = wn * 64 + n_ * 16 + l15;                              \
        (BV)[n_] = *(const short8*)&S[(BUF) * 32768 + 16384 + row_ * 64 +      \
                 (((KS) * 32 + lg * 8) ^ ((row_ & 7) << 3))]; } } while (0)

#define DO_MFMA(MH, BV) do { __builtin_amdgcn_s_setprio(1); _Pragma("unroll")  \
    for (int m_ = 0; m_ < 4; ++m_) { _Pragma("unroll")                         \
        for (int n_ = 0; n_ < 4; ++n_)                                         \
            acc[(MH) * 4 + m_][n_] = __builtin_amdgcn_mfma_f32_16x16x32_bf16(  \
                av[m_], (BV)[n_], acc[(MH) * 4 + m_][n_], 0, 0, 0); }          \
    __builtin_amdgcn_s_setprio(0); } while (0)

#define BAR() __builtin_amdgcn_s_barrier()

    stageB(0, 0); stageB(0, 1); stageA(0, 0); stageA(0, 1);
    stageB(1, 0); stageB(1, 1);
    asm volatile("s_waitcnt vmcnt(4)" ::: "memory");
    BAR();

    for (int it = 0; it < 4; ++it) {
        const int T1 = 2 * it + 1;
        RD_B(0, 0, bv0); RD_A(0, 0, 0); stageA(T1, 0);
        BAR(); DO_MFMA(0, bv0); BAR();
        RD_B(0, 1, bv1); RD_A(0, 0, 1); stageA(T1, 1);
        BAR(); DO_MFMA(0, bv1); BAR();
        RD_A(0, 1, 0); stageB(T1 + 1, 0);
        BAR(); DO_MFMA(1, bv0); BAR();
        RD_A(0, 1, 1); stageB(T1 + 1, 1);
        BAR(); DO_MFMA(1, bv1);
        if (it == 3) asm volatile("s_waitcnt vmcnt(0)" ::: "memory");
        else         asm volatile("s_waitcnt vmcnt(4)" ::: "memory");
        BAR();
        RD_B(1, 0, bv0); RD_A(1, 0, 0); stageA(T1 + 1, 0);
        BAR(); DO_MFMA(0, bv0); BAR();
        RD_B(1, 1, bv1); RD_A(1, 0, 1); stageA(T1 + 1, 1);
        BAR(); DO_MFMA(0, bv1); BAR();
        RD_A(1, 1, 0); stageB(T1 + 2, 0);
        BAR(); DO_MFMA(1, bv0); BAR();
        RD_A(1, 1, 1); stageB(T1 + 2, 1);
        BAR(); DO_MFMA(1, bv1);
        if (it < 3) asm volatile("s_waitcnt vmcnt(4)" ::: "memory");
        BAR();
    }

    #pragma unroll
    for (int mi = 0; mi < 8; ++mi) {
        #pragma unroll
        for (int n = 0; n < 4; ++n) {
            #pragma unroll
            for (int r = 0; r < 4; ++r) {
                const long row = row0 + wm * 128 + mi * 16 + lg * 4 + r;
                const long col = col0 + wn * 64 + n * 16 + l15;
                const float v = acc[mi][n][r];
                C[row * 512 + col] = __float2bfloat16(v > 0.f ? v : 0.f);
            }
        }
    }
#undef RD_A
#undef RD_B
#undef DO_MFMA
#undef BAR
}

// ---------------------------------------------------------------------------
// W2 GEMM + LN2 + residual, 8-PHASE 256x256 schedule (same K-loop as W1_8p).
// out = fp32 x + LN(t @ W2). M=32768, N=256 (=BN, col0=0), K=512.
// Grid 128 blocks x 512 thr (8 waves, 2M x 4N; per-wave 128x64 output).
// A = t_bf (stride 512); B = whole W2T (L2-resident). LN arrays alias the
// dead staging LDS after the final drain.
// ---------------------------------------------------------------------------
__global__ __launch_bounds__(512, 2)
void k_ln2_8p(const bf16* __restrict__ A, const bf16* __restrict__ BT,
              const float* __restrict__ g, const float* __restrict__ b,
              const float* __restrict__ xres, float* __restrict__ out)
{
    __shared__ __attribute__((aligned(16))) bf16 S[65536];   // 128 KB
    const int t = threadIdx.x, w = t >> 6, lane = t & 63;
    const int wm = w >> 2, wn = w & 3;
    const int lg = lane >> 4, l15 = lane & 15;
    const int orig = blockIdx.x;                             // 0..127
    const int swz  = (orig & 7) * 16 + (orig >> 3);          // bijective XCD
    const long row0 = (long)swz * 256;

    f32x4 acc[8][4] = {};
    short8 av[4], bv0[4], bv1[4];

    auto stageA = [&](int tile, int half) {
        if (tile >= 8) return;
        const int kbase = tile * 64;
        #pragma unroll
        for (int i = 0; i < 2; ++i) {
            const int cbase = i * 512 + w * 64;
            const int c = cbase + lane;
            const int srow = c >> 3;
            const int lcol = 8 * ((c & 7) ^ (srow & 7));
            async16(A + (row0 + half * 128 + srow) * 512 + kbase + lcol,
                    &S[(tile & 1) * 32768 + half * 8192 + cbase * 8]);
        }
    };
    auto stageB = [&](int tile, int half) {
        if (tile >= 8) return;
        const int kbase = tile * 64;
        #pragma unroll
        for (int i = 0; i < 2; ++i) {
            const int cbase = i * 512 + w * 64;
            const int c = cbase + lane;
            const int srow = c >> 3;
            const int lcol = 8 * ((c & 7) ^ (srow & 7));
            async16(BT + (long)(half * 128 + srow) * 512 + kbase + lcol,
                    &S[(tile & 1) * 32768 + 16384 + half * 8192 + cbase * 8]);
        }
    };

#define RD_A(BUF, MH, KS) do { _Pragma("unroll")                               \
    for (int m_ = 0; m_ < 4; ++m_) {                                           \
        const int row_ = wm * 128 + (MH) * 64 + m_ * 16 + l15;                 \
        av[m_] = *(const short8*)&S[(BUF) * 32768 + row_ * 64 +                \
                 (((KS) * 32 + lg * 8) ^ ((row_ & 7) << 3))]; } } while (0)

#define RD_B(BUF, KS, BV) do { _Pragma("unroll")                               \
    for (int n_ = 0; n_ < 4; ++n_) {                                           \
        const int row_ = wn * 64 + n_ * 16 + l15;                              \
        (BV)[n_] = *(const short8*)&S[(BUF) * 32768 + 16384 + row_ * 64 +      \
                 (((KS) * 32 + lg * 8) ^ ((row_ & 7) << 3))]; } } while (0)

#define DO_MFMA(MH, BV) do { __builtin_amdgcn_s_setprio(1); _Pragma("unroll")  \
    for (int m_ = 0; m_ < 4; ++m_) { _Pragma("unroll")                         \
        for (int n_ = 0; n_ < 4; ++n_)                                         \
            acc[(MH) * 4 + m_][n_] = __builtin_amdgcn_mfma_f32_16x16x32_bf16(  \
                av[m_], (BV)[n_], acc[(MH) * 4 + m_][n_], 0, 0, 0); }          \
    __builtin_amdgcn_s_setprio(0); } while (0)

#define BAR() __builtin_amdgcn_s_barrier()

    stageB(0, 0); stageB(0, 1); stageA(0, 0); stageA(0, 1);
    stageB(1, 0); stageB(1, 1);
    asm volatile("s_waitcnt vmcnt(4)" ::: "memory");
    BAR();

    for (int it = 0; it < 4; ++it) {
        const int T1 = 2 * it + 1;
        RD_B(0, 0, bv0); RD_A(0, 0, 0); stageA(T1, 0);
        BAR(); DO_MFMA(0, bv0); BAR();
        RD_B(0, 1, bv1); RD_A(0, 0, 1); stageA(T1, 1);
        BAR(); DO_MFMA(0, bv1); BAR();
        RD_A(0, 1, 0); stageB(T1 + 1, 0);
        BAR(); DO_MFMA(1, bv0); BAR();
        RD_A(0, 1, 1); stageB(T1 + 1, 1);
        BAR(); DO_MFMA(1, bv1);
        if (it == 3) asm volatile("s_waitcnt vmcnt(0)" ::: "memory");
        else         asm volatile("s_waitcnt vmcnt(4)" ::: "memory");
        BAR();
        RD_B(1, 0, bv0); RD_A(1, 0, 0); stageA(T1 + 1, 0);
        BAR(); DO_MFMA(0, bv0); BAR();
        RD_B(1, 1, bv1); RD_A(1, 0, 1); stageA(T1 + 1, 1);
        BAR(); DO_MFMA(0, bv1); BAR();
        RD_A(1, 1, 0); stageB(T1 + 2, 0);
        BAR(); DO_MFMA(1, bv0); BAR();
        RD_A(1, 1, 1); stageB(T1 + 2, 1);
        BAR(); DO_MFMA(1, bv1);
        if (it < 3) asm volatile("s_waitcnt vmcnt(4)" ::: "memory");
        BAR();
    }

    // ---- LN2 + residual epilogue; lnS/lnQ alias the dead staging LDS ----
    __syncthreads();                     // all LDS reads drained
    float* lnS = (float*)S;              // [4][256] = 4 KB
    float* lnQ = (float*)((char*)S + 4096);

    #pragma unroll
    for (int mi = 0; mi < 8; ++mi) {
        #pragma unroll
        for (int r = 0; r < 4; ++r) {
            float ls = 0.f, lq = 0.f;
            #pragma unroll
            for (int n = 0; n < 4; ++n) {
                const float v = acc[mi][n][r];
                ls += v; lq += v * v;
            }
            #pragma unroll
            for (int o = 1; o < 16; o <<= 1) {
                ls += __shfl_xor(ls, o);
                lq += __shfl_xor(lq, o);
            }
            if (l15 == 0) {
                const int row = wm * 128 + mi * 16 + lg * 4 + r;
                lnS[wn * 256 + row] = ls;
                lnQ[wn * 256 + row] = lq;
            }
        }
    }
    __syncthreads();

    float gv[4], bv[4];
    #pragma unroll
    for (int n = 0; n < 4; ++n) {
        const int col = wn * 64 + n * 16 + l15;
        gv[n] = g[col]; bv[n] = b[col];
    }
    #pragma unroll
    for (int mi = 0; mi < 8; ++mi) {
        #pragma unroll
        for (int r = 0; r < 4; ++r) {
            const int row = wm * 128 + mi * 16 + lg * 4 + r;
            const float Sm = lnS[row] + lnS[256 + row] + lnS[512 + row] + lnS[768 + row];
            const float Qq = lnQ[row] + lnQ[256 + row] + lnQ[512 + row] + lnQ[768 + row];
            const float mean = Sm * (1.f / 256.f);
            const float var  = Qq * (1.f / 256.f) - mean * mean;
            const float rstd = rsqrtf(var + EPS_LN);
            const long grow = row0 + row;
            #pragma unroll
            for (int n = 0; n < 4; ++n) {
                const int col = wn * 64 + n * 16 + l15;
                const float y = (acc[mi][n][r] - mean) * rstd * gv[n] + bv[n];
                out[grow * 256 + col] = xres[grow * 256 + col] + y;
            }
        }
    }
#undef RD_A
#undef RD_B
#undef DO_MFMA
#undef BAR
}

// ---------------------------------------------------------------------------
extern "C" void kernel_launch(void* const* d_in, const int* in_sizes, int n_in,
                              void* d_out, int out_size, void* d_ws, size_t ws_size,
                              hipStream_t stream)
{
    const float* x      = (const float*)d_in[0];
    const float* source = (const float*)d_in[1];
    const float* Wq     = (const float*)d_in[2];
    const float* Wk     = (const float*)d_in[3];
    const float* Wv     = (const float*)d_in[4];
    const float* Wm     = (const float*)d_in[5];
    const float* W1     = (const float*)d_in[6];
    const float* W2     = (const float*)d_in[7];
    const float* g1     = (const float*)d_in[8];
    const float* b1     = (const float*)d_in[9];
    const float* g2     = (const float*)d_in[10];
    const float* b2     = (const float*)d_in[11];
    float* out = (float*)d_out;

    const size_t U = 32768ull * 256ull;
    char* w = (char*)d_ws;

    // slots (16 MB each); lifetimes:
    bf16* x_bf  = (bf16*)(w + 0 * U * 2);   // alive through W1 gemm
    bf16* s_bf  = (bf16*)(w + 1 * U * 2);   // dead after k_kvproj
    bf16* msgln = (bf16*)(w + 2 * U * 2);   // qaml out, alive through W1
    bf16* t_bf  = (bf16*)(w + 3 * U * 2);   // slots 3-4 ([32768,512])

    char* wx = w + 7 * U * 2;
    bf16* WqT = (bf16*)wx; wx += 65536 * 2;
    bf16* WkT = (bf16*)wx; wx += 65536 * 2;   // contiguous with WvT -> [512][256]
    bf16* WvT = (bf16*)wx; wx += 65536 * 2;
    bf16* WmT = (bf16*)wx; wx += 65536 * 2;
    bf16* W1T = (bf16*)wx; wx += 262144 * 2;
    bf16* W2T = (bf16*)wx; wx += 131072 * 2;
    bf16* partKV = (bf16*)wx; wx += 2097152 * 2;   // 256 cid x 8192
    float* partKs = (float*)wx; wx += 65536 * 4;   // 256 cid x 256
    bf16* part2  = (bf16*)wx; wx += 262144 * 2;    // 8 x 4 x 8192
    float* part2Ks = (float*)wx; wx += 8192 * 4;   // 8 x 4 x 256
    bf16* KVb    = (bf16*)wx; wx += 49152 * 2;     // [n][h][32][48]

    const dim3 blk(256);

    // 1) prep: converts + all weight transposes (one launch)
    k_prep<<<8352, blk, 0, stream>>>(x, source, x_bf, s_bf,
                                     Wq, Wk, Wv, Wm, W1, W2,
                                     WqT, WkT, WvT, WmT, W1T, W2T);

    // 2) FUSED K/V projection + partial KV/Ksum
    k_kvproj<<<dim3(256, 2), dim3(512), 0, stream>>>(s_bf, WkT, partKV, partKs,
                                                     1.f / 8192.f);

    // 3) reduce partials -> KVaug
    k_kvred1<<<256, blk, 0, stream>>>(partKV, partKs, part2, part2Ks);
    k_kvred2<<<32, blk, 0, stream>>>(part2, part2Ks, KVb);

    // 4) MEGA: Q-proj + attn + merge + LN1 -> msgln
    k_qaml<<<512, dim3(512), 0, stream>>>(x_bf, WqT, WmT, KVb, g1, b1, msgln);

    // 5) MLP: t = relu([x_bf|msgln]@W1) via 8-PHASE; out = x + LN2(t@W2) 8-PHASE
    k_gemmW1_8p<<<dim3(128, 2), dim3(512), 0, stream>>>(x_bf, msgln, W1T, t_bf);
    k_ln2_8p<<<128, dim3(512), 0, stream>>>(t_bf, W2T, g2, b2, x, out);
}